// Round 2
// baseline (5415.333 us; speedup 1.0000x reference)
//
#include <hip/hip_runtime.h>

constexpr int B = 4, N = 8192, S = 512, K = 16, F = 128, H = 128;
constexpr float EPS = 1e-5f;

// ---------------------------------------------------------------- layernorm
__global__ __launch_bounds__(128) void ln_kernel(const float* __restrict__ features,
    const float* __restrict__ g, const float* __restrict__ bta, float* __restrict__ feats) {
  int r = blockIdx.x, t = threadIdx.x;
  __shared__ float red[128];
  float v = features[(size_t)r * F + t];
  red[t] = v; __syncthreads();
  #pragma unroll
  for (int off = 64; off > 0; off >>= 1) { if (t < off) red[t] += red[t + off]; __syncthreads(); }
  float m = red[0] * (1.f / F);
  __syncthreads();
  float d = v - m;
  red[t] = d * d; __syncthreads();
  #pragma unroll
  for (int off = 64; off > 0; off >>= 1) { if (t < off) red[t] += red[t + off]; __syncthreads(); }
  float var = red[0] * (1.f / F);
  float rstd = rsqrtf(var + EPS);
  feats[(size_t)r * F + t] = d * rstd * g[t] + bta[t];
}

// ---------------------------------------------------------------- FPS (sequential, 1 block per batch)
__global__ __launch_bounds__(1024) void fps_kernel(const float* __restrict__ xyzp,
    int* __restrict__ fps_idx, float* __restrict__ new_xyz) {
  int b = blockIdx.x, t = threadIdx.x;
  const float4* xp = (const float4*)(xyzp + (size_t)b * N * 4);
  float px[8], py[8], pz[8], mind[8];
  #pragma unroll
  for (int j = 0; j < 8; j++) {
    float4 p = xp[t + 1024 * j];
    px[j] = p.x; py[j] = p.y; pz[j] = p.z;
    mind[j] = 1e10f;
  }
  __shared__ float wval[16];
  __shared__ int widx[16];
  __shared__ int s_last;
  int last = 0;
  if (t == 0) fps_idx[b * S] = 0;
  if (t == 0) {
    float4 p0 = xp[0];
    new_xyz[((size_t)b * S) * 3 + 0] = p0.x;
    new_xyz[((size_t)b * S) * 3 + 1] = p0.y;
    new_xyz[((size_t)b * S) * 3 + 2] = p0.z;
  }
  for (int s = 1; s < S; ++s) {
    float4 lp = xp[last];
    float lx = lp.x, ly = lp.y, lz = lp.z;
    float bv = -1.f; int bi = 0;
    #pragma unroll
    for (int j = 0; j < 8; j++) {
      float dx = __fsub_rn(px[j], lx), dy = __fsub_rn(py[j], ly), dz = __fsub_rn(pz[j], lz);
      float d = __fadd_rn(__fadd_rn(__fmul_rn(dx, dx), __fmul_rn(dy, dy)), __fmul_rn(dz, dz));
      mind[j] = fminf(mind[j], d);
      if (mind[j] > bv) { bv = mind[j]; bi = t + 1024 * j; }   // strict > : lowest idx in-lane on tie
    }
    #pragma unroll
    for (int off = 32; off > 0; off >>= 1) {
      float ov = __shfl_down(bv, off); int oi = __shfl_down(bi, off);
      if (ov > bv || (ov == bv && oi < bi)) { bv = ov; bi = oi; }
    }
    int wid = t >> 6, lane = t & 63;
    if (lane == 0) { wval[wid] = bv; widx[wid] = bi; }
    __syncthreads();
    if (t == 0) {
      float v = wval[0]; int i = widx[0];
      for (int w = 1; w < 16; w++) {
        float ov = wval[w]; int oi = widx[w];
        if (ov > v || (ov == v && oi < i)) { v = ov; i = oi; }
      }
      s_last = i; fps_idx[b * S + s] = i;
      float4 p = xp[i];
      new_xyz[((size_t)b * S + s) * 3 + 0] = p.x;
      new_xyz[((size_t)b * S + s) * 3 + 1] = p.y;
      new_xyz[((size_t)b * S + s) * 3 + 2] = p.z;
    }
    __syncthreads();
    last = s_last;
  }
}

// ---------------------------------------------------------------- kNN: 512 queries vs 8192 refs
__global__ __launch_bounds__(256) void knn_dn_kernel(const float* __restrict__ xyzp,
    const float* __restrict__ new_xyz, int* __restrict__ idx_dn, float* __restrict__ new_xyzp) {
  __shared__ __align__(16) float4 refs[1024];
  int b = blockIdx.x >> 1;
  int s = ((blockIdx.x & 1) << 8) + threadIdx.x;
  const float4* xp = (const float4*)(xyzp + (size_t)b * N * 4);
  float qx = new_xyz[((size_t)b * S + s) * 3 + 0];
  float qy = new_xyz[((size_t)b * S + s) * 3 + 1];
  float qz = new_xyz[((size_t)b * S + s) * 3 + 2];
  float qq = __fadd_rn(__fadd_rn(__fmul_rn(qx, qx), __fmul_rn(qy, qy)), __fmul_rn(qz, qz));
  float bd[16]; int bix[16];
  #pragma unroll
  for (int j = 0; j < 16; j++) { bd[j] = 3e38f; bix[j] = 0; }
  for (int c0 = 0; c0 < N; c0 += 1024) {
    __syncthreads();
    for (int u = threadIdx.x; u < 1024; u += 256) {
      float4 p = xp[c0 + u];
      float rr = __fadd_rn(__fadd_rn(__fmul_rn(p.x, p.x), __fmul_rn(p.y, p.y)), __fmul_rn(p.z, p.z));
      refs[u] = make_float4(p.x, p.y, p.z, rr);
    }
    __syncthreads();
    for (int u = 0; u < 1024; u++) {
      float4 rv = refs[u];
      float dot = __fadd_rn(__fadd_rn(__fmul_rn(qx, rv.x), __fmul_rn(qy, rv.y)), __fmul_rn(qz, rv.z));
      float d2 = __fsub_rn(__fadd_rn(qq, rv.w), __fmul_rn(2.0f, dot));
      if (d2 < bd[15]) {
        bd[15] = d2; bix[15] = c0 + u;
        #pragma unroll
        for (int j = 15; j > 0; --j) {
          if (bd[j] < bd[j - 1]) {
            float td = bd[j]; bd[j] = bd[j - 1]; bd[j - 1] = td;
            int ti = bix[j]; bix[j] = bix[j - 1]; bix[j - 1] = ti;
          }
        }
      }
    }
  }
  size_t base = ((size_t)b * S + s) * K;
  #pragma unroll
  for (int j = 0; j < 16; j++) idx_dn[base + j] = bix[j];
  float4 nnp = xp[bix[0]];
  *(float4*)&new_xyzp[((size_t)b * S + s) * 4] = nnp;
}

// ---------------------------------------------------------------- kNN: 8192 queries vs 512 refs
__global__ __launch_bounds__(256) void knn_up_kernel(const float* __restrict__ xyzp,
    const float* __restrict__ new_xyz, int* __restrict__ idx_up) {
  __shared__ __align__(16) float4 refs[512];
  int b = blockIdx.x >> 5;
  int n = ((blockIdx.x & 31) << 8) + threadIdx.x;
  for (int u = threadIdx.x; u < 512; u += 256) {
    float x = new_xyz[((size_t)b * S + u) * 3 + 0];
    float y = new_xyz[((size_t)b * S + u) * 3 + 1];
    float z = new_xyz[((size_t)b * S + u) * 3 + 2];
    float rr = __fadd_rn(__fadd_rn(__fmul_rn(x, x), __fmul_rn(y, y)), __fmul_rn(z, z));
    refs[u] = make_float4(x, y, z, rr);
  }
  __syncthreads();
  const float4* xp = (const float4*)(xyzp + (size_t)b * N * 4);
  float4 qp = xp[n];
  float qx = qp.x, qy = qp.y, qz = qp.z;
  float qq = __fadd_rn(__fadd_rn(__fmul_rn(qx, qx), __fmul_rn(qy, qy)), __fmul_rn(qz, qz));
  float bd[16]; int bix[16];
  #pragma unroll
  for (int j = 0; j < 16; j++) { bd[j] = 3e38f; bix[j] = 0; }
  for (int u = 0; u < 512; u++) {
    float4 rv = refs[u];
    float dot = __fadd_rn(__fadd_rn(__fmul_rn(qx, rv.x), __fmul_rn(qy, rv.y)), __fmul_rn(qz, rv.z));
    float d2 = __fsub_rn(__fadd_rn(qq, rv.w), __fmul_rn(2.0f, dot));
    if (d2 < bd[15]) {
      bd[15] = d2; bix[15] = u;
      #pragma unroll
      for (int j = 15; j > 0; --j) {
        if (bd[j] < bd[j - 1]) {
          float td = bd[j]; bd[j] = bd[j - 1]; bd[j - 1] = td;
          int ti = bix[j]; bix[j] = bix[j - 1]; bix[j - 1] = ti;
        }
      }
    }
  }
  size_t base = ((size_t)b * N + n) * K;
  #pragma unroll
  for (int j = 0; j < 16; j++) idx_up[base + j] = bix[j];
}

// ---------------------------------------------------------------- grouped MLP layer 0 (131 -> 128)
__global__ __launch_bounds__(128) void td0_kernel(const float* __restrict__ xyzp,
    const float* __restrict__ new_xyz, const float* __restrict__ feats,
    const int* __restrict__ idx_dn, const float* __restrict__ w0, const float* __restrict__ b0,
    float* __restrict__ act0) {
  int rowid = blockIdx.x, t = threadIdx.x;
  int b = rowid >> 13;
  int s = (rowid >> 4) & (S - 1);
  __shared__ float row[131];
  int idxn = idx_dn[rowid];
  if (t < 3) row[t] = xyzp[((size_t)b * N + idxn) * 4 + t] - new_xyz[((size_t)b * S + s) * 3 + t];
  row[3 + t] = feats[((size_t)b * N + idxn) * F + t];
  __syncthreads();
  float acc = b0[t];
  for (int i = 0; i < 131; i++) acc = fmaf(row[i], w0[i * F + t], acc);
  act0[(size_t)rowid * F + t] = acc;
}

// ---------------------------------------------------------------- batchnorm stats
__global__ __launch_bounds__(256) void bn_reduce_kernel(const float* __restrict__ x,
                                                        float* __restrict__ sums) {
  __shared__ float ls[256], ls2[256];
  int t = threadIdx.x;
  size_t base = (size_t)blockIdx.x * 65536 + t;
  float s = 0.f, s2 = 0.f;
  for (int i = 0; i < 256; i++) {
    float v = x[base + (size_t)i * 256];
    s += v; s2 = fmaf(v, v, s2);
  }
  ls[t] = s; ls2[t] = s2; __syncthreads();
  if (t < 128) {
    s = ls[t] + ls[t + 128]; s2 = ls2[t] + ls2[t + 128];
    atomicAdd(&sums[t], s); atomicAdd(&sums[128 + t], s2);
  }
}

__global__ void bn_finalize_kernel(const float* __restrict__ sums, const float* __restrict__ g,
    const float* __restrict__ bta, float* __restrict__ scale, float* __restrict__ shift) {
  int t = threadIdx.x;
  float m = sums[t] * (1.f / 32768.f);
  float var = sums[128 + t] * (1.f / 32768.f) - m * m;
  float rstd = rsqrtf(var + EPS);
  float sc = g[t] * rstd;
  scale[t] = sc;
  shift[t] = bta[t] - m * sc;
}

// ---------------------------------------------------------------- grouped MLP layer 1 (128 -> 128)
__global__ __launch_bounds__(128) void td1_kernel(const float* __restrict__ act0,
    const float* __restrict__ scale, const float* __restrict__ shift,
    const float* __restrict__ w1, const float* __restrict__ b1, float* __restrict__ act1) {
  int rowid = blockIdx.x, t = threadIdx.x;
  __shared__ float row[128];
  float xn = fmaxf(fmaf(act0[(size_t)rowid * F + t], scale[t], shift[t]), 0.f);
  row[t] = xn; __syncthreads();
  float acc = b1[t];
  for (int i = 0; i < F; i++) acc = fmaf(row[i], w1[i * F + t], acc);
  act1[(size_t)rowid * F + t] = acc;
}

// ---------------------------------------------------------------- BN+relu+max over K
__global__ __launch_bounds__(128) void maxpool_kernel(const float* __restrict__ act1,
    const float* __restrict__ scale, const float* __restrict__ shift, float* __restrict__ new_feats) {
  int bs = blockIdx.x, t = threadIdx.x;
  float sc = scale[t], sh = shift[t];
  float m = -3e38f;
  for (int k = 0; k < K; k++) {
    float v = fmaxf(fmaf(act1[((size_t)bs * K + k) * F + t], sc, sh), 0.f);
    m = fmaxf(m, v);
  }
  new_feats[(size_t)bs * F + t] = m;
}

// ---------------------------------------------------------------- new_x = new_feats @ w_gkern + b
__global__ __launch_bounds__(128) void rowgemm_kernel(const float* __restrict__ in,
    const float* __restrict__ w, const float* __restrict__ bias, float* __restrict__ out) {
  int r = blockIdx.x, t = threadIdx.x;
  __shared__ float row[128];
  row[t] = in[(size_t)r * F + t]; __syncthreads();
  float acc = bias[t];
  for (int i = 0; i < F; i++) acc = fmaf(row[i], w[i * F + t], acc);
  out[(size_t)r * F + t] = acc;
}

// ---------------------------------------------------------------- kk/vv = new_x @ w_k / w_v
__global__ __launch_bounds__(128) void kv_kernel(const float* __restrict__ new_x,
    const float* __restrict__ wk, const float* __restrict__ wvp,
    float* __restrict__ kk, float* __restrict__ vv) {
  int r = blockIdx.x, t = threadIdx.x;
  __shared__ float row[128];
  row[t] = new_x[(size_t)r * F + t]; __syncthreads();
  float ak = 0.f, av = 0.f;
  for (int i = 0; i < F; i++) {
    float x = row[i];
    ak = fmaf(x, wk[i * F + t], ak);
    av = fmaf(x, wvp[i * F + t], av);
  }
  kk[(size_t)r * F + t] = ak;
  vv[(size_t)r * F + t] = av;
}

// ---------------------------------------------------------------- q = (feats @ w_kern + b) @ w_q
__global__ __launch_bounds__(128) void q_kernel(const float* __restrict__ feats,
    const float* __restrict__ w_kern, const float* __restrict__ b_kern,
    const float* __restrict__ w_q, float* __restrict__ q) {
  int r = blockIdx.x, t = threadIdx.x;
  __shared__ float row[128], row2[128];
  row[t] = feats[(size_t)r * F + t]; __syncthreads();
  float acc = b_kern[t];
  for (int i = 0; i < F; i++) acc = fmaf(row[i], w_kern[i * F + t], acc);
  row2[t] = acc; __syncthreads();
  float aq = 0.f;
  for (int i = 0; i < F; i++) aq = fmaf(row2[i], w_q[i * F + t], aq);
  q[(size_t)r * F + t] = aq;
}

// ---------------------------------------------------------------- fused neighbor attention + epilogue
__global__ __launch_bounds__(128) void attn_kernel(const float* __restrict__ xyzp,
    const float* __restrict__ q, const float* __restrict__ kk, const float* __restrict__ vv,
    const float* __restrict__ new_xyzp, const int* __restrict__ idx_up,
    const float* __restrict__ feats,
    const float* __restrict__ pe_w1, const float* __restrict__ pe_b1,
    const float* __restrict__ pe_w2, const float* __restrict__ pe_b2,
    const float* __restrict__ at_w1, const float* __restrict__ at_b1,
    const float* __restrict__ at_w2, const float* __restrict__ at_b2,
    const float* __restrict__ w_agg, const float* __restrict__ b_agg,
    float* __restrict__ out) {
  int p = blockIdx.x, t = threadIdx.x;
  int b = p >> 13;
  __shared__ float qs[128];
  __shared__ float pd[16][4];
  __shared__ int nb[16];
  __shared__ __align__(16) float buf1[16][128];   // peh, then tact
  __shared__ __align__(16) float av[16][128];
  __shared__ __align__(16) float wv[16][128];
  qs[t] = q[(size_t)p * H + t];
  if (t < 16) nb[t] = idx_up[(size_t)p * K + t];
  __syncthreads();
  if (t < 64) {
    int k = t >> 2, d = t & 3;
    pd[k][d] = xyzp[(size_t)p * 4 + d] - new_xyzp[((size_t)b * S + nb[k]) * 4 + d];
  }
  __syncthreads();
  { // pe layer 1: 4 -> 128, relu
    float bb = pe_b1[t];
    float w0 = pe_w1[0 * H + t], w1 = pe_w1[1 * H + t];
    float w2 = pe_w1[2 * H + t], w3 = pe_w1[3 * H + t];
    #pragma unroll
    for (int k = 0; k < 16; k++) {
      float h = bb + pd[k][0] * w0 + pd[k][1] * w1 + pd[k][2] * w2 + pd[k][3] * w3;
      buf1[k][t] = fmaxf(h, 0.f);
    }
  }
  __syncthreads();
  { // pe layer 2 -> pos_enc; build av / wv
    float acc[16];
    float bb = pe_b2[t];
    #pragma unroll
    for (int k = 0; k < 16; k++) acc[k] = bb;
    for (int i4 = 0; i4 < H / 4; i4++) {
      int i = i4 * 4;
      float w0 = pe_w2[(i + 0) * H + t], w1 = pe_w2[(i + 1) * H + t];
      float w2 = pe_w2[(i + 2) * H + t], w3 = pe_w2[(i + 3) * H + t];
      #pragma unroll
      for (int k = 0; k < 16; k++) {
        float4 x = *(const float4*)&buf1[k][i];
        acc[k] = fmaf(x.x, w0, acc[k]); acc[k] = fmaf(x.y, w1, acc[k]);
        acc[k] = fmaf(x.z, w2, acc[k]); acc[k] = fmaf(x.w, w3, acc[k]);
      }
    }
    #pragma unroll
    for (int k = 0; k < 16; k++) {
      int s = nb[k];
      float kkv = kk[((size_t)b * S + s) * H + t];
      float vvv = vv[((size_t)b * S + s) * H + t];
      av[k][t] = qs[t] - kkv + acc[k];
      wv[k][t] = vvv + acc[k];
    }
  }
  __syncthreads();
  { // attn MLP layer 1: relu(av @ at_w1 + b) -> buf1
    float acc[16];
    float bb = at_b1[t];
    #pragma unroll
    for (int k = 0; k < 16; k++) acc[k] = bb;
    for (int i4 = 0; i4 < H / 4; i4++) {
      int i = i4 * 4;
      float w0 = at_w1[(i + 0) * H + t], w1 = at_w1[(i + 1) * H + t];
      float w2 = at_w1[(i + 2) * H + t], w3 = at_w1[(i + 3) * H + t];
      #pragma unroll
      for (int k = 0; k < 16; k++) {
        float4 x = *(const float4*)&av[k][i];
        acc[k] = fmaf(x.x, w0, acc[k]); acc[k] = fmaf(x.y, w1, acc[k]);
        acc[k] = fmaf(x.z, w2, acc[k]); acc[k] = fmaf(x.w, w3, acc[k]);
      }
    }
    #pragma unroll
    for (int k = 0; k < 16; k++) buf1[k][t] = fmaxf(acc[k], 0.f);
  }
  __syncthreads();
  float lg[16];
  { // attn MLP layer 2 -> logits (kept in registers, per channel)
    float bb = at_b2[t];
    #pragma unroll
    for (int k = 0; k < 16; k++) lg[k] = bb;
    for (int i4 = 0; i4 < H / 4; i4++) {
      int i = i4 * 4;
      float w0 = at_w2[(i + 0) * H + t], w1 = at_w2[(i + 1) * H + t];
      float w2 = at_w2[(i + 2) * H + t], w3 = at_w2[(i + 3) * H + t];
      #pragma unroll
      for (int k = 0; k < 16; k++) {
        float4 x = *(const float4*)&buf1[k][i];
        lg[k] = fmaf(x.x, w0, lg[k]); lg[k] = fmaf(x.y, w1, lg[k]);
        lg[k] = fmaf(x.z, w2, lg[k]); lg[k] = fmaf(x.w, w3, lg[k]);
      }
    }
  }
  float res = 0.f;
  { // per-channel softmax over the 16 neighbors (all in registers)
    float m = -3e38f;
    #pragma unroll
    for (int k = 0; k < 16; k++) { lg[k] = lg[k] / 11.3137085f; m = fmaxf(m, lg[k]); }
    float sum = 0.f;
    #pragma unroll
    for (int k = 0; k < 16; k++) { lg[k] = expf(lg[k] - m); sum += lg[k]; }
    float inv = 1.f / sum;
    #pragma unroll
    for (int k = 0; k < 16; k++) res = fmaf(lg[k] * inv, wv[k][t], res);
  }
  __syncthreads();
  qs[t] = res;
  __syncthreads();
  float o = b_agg[t];
  for (int i = 0; i < H; i++) o = fmaf(qs[i], w_agg[i * H + t], o);
  o += feats[(size_t)p * F + t];
  out[(size_t)p * F + t] = o;
}

// ================================================================ host
extern "C" void kernel_launch(void* const* d_in, const int* in_sizes, int n_in,
                              void* d_out, int out_size, void* d_ws, size_t ws_size,
                              hipStream_t stream) {
  (void)in_sizes; (void)n_in; (void)out_size; (void)ws_size;
  const float* xyzp    = (const float*)d_in[0];
  const float* features= (const float*)d_in[1];
  const float* ln_g    = (const float*)d_in[2];
  const float* ln_b    = (const float*)d_in[3];
  const float* td_w0   = (const float*)d_in[4];
  const float* td_b0   = (const float*)d_in[5];
  const float* bn0_g   = (const float*)d_in[6];
  const float* bn0_b   = (const float*)d_in[7];
  const float* td_w1   = (const float*)d_in[8];
  const float* td_b1   = (const float*)d_in[9];
  const float* bn1_g   = (const float*)d_in[10];
  const float* bn1_b   = (const float*)d_in[11];
  const float* w_kern  = (const float*)d_in[12];
  const float* b_kern  = (const float*)d_in[13];
  const float* w_gkern = (const float*)d_in[14];
  const float* b_gkern = (const float*)d_in[15];
  const float* w_agg   = (const float*)d_in[16];
  const float* b_agg   = (const float*)d_in[17];
  const float* w_q     = (const float*)d_in[18];
  const float* w_k     = (const float*)d_in[19];
  const float* w_v     = (const float*)d_in[20];
  const float* pe_w1   = (const float*)d_in[21];
  const float* pe_b1   = (const float*)d_in[22];
  const float* pe_w2   = (const float*)d_in[23];
  const float* pe_b2   = (const float*)d_in[24];
  const float* at_w1   = (const float*)d_in[25];
  const float* at_b1   = (const float*)d_in[26];
  const float* at_w2   = (const float*)d_in[27];
  const float* at_b2   = (const float*)d_in[28];
  float* out = (float*)d_out;

  float* wsf = (float*)d_ws;
  float* feats     = wsf + 0;           // 4194304
  float* q         = wsf + 4194304;     // 4194304
  float* act0      = wsf + 8388608;     // 4194304
  float* act1      = wsf + 12582912;    // 4194304
  float* new_feats = wsf + 16777216;    // 262144
  float* new_x     = wsf + 17039360;    // 262144
  float* kk        = wsf + 17301504;    // 262144
  float* vv        = wsf + 17563648;    // 262144
  float* new_xyz   = wsf + 17825792;    // 6144
  float* new_xyzp  = wsf + 17831936;    // 8192
  float* sums0     = wsf + 17840128;    // 256
  float* sums1     = wsf + 17840384;    // 256
  float* sc0       = wsf + 17840640;    // 128
  float* sh0       = wsf + 17840768;    // 128
  float* sc1       = wsf + 17840896;    // 128
  float* sh1       = wsf + 17841024;    // 128
  int* fps_idx = (int*)(wsf + 17841152);
  int* idx_dn  = fps_idx + 2048;
  int* idx_up  = idx_dn + 32768;

  hipMemsetAsync(sums0, 0, 512 * sizeof(float), stream);
  ln_kernel<<<B * N, 128, 0, stream>>>(features, ln_g, ln_b, feats);
  fps_kernel<<<B, 1024, 0, stream>>>(xyzp, fps_idx, new_xyz);
  knn_dn_kernel<<<8, 256, 0, stream>>>(xyzp, new_xyz, idx_dn, new_xyzp);
  knn_up_kernel<<<128, 256, 0, stream>>>(xyzp, new_xyz, idx_up);
  td0_kernel<<<B * S * K, 128, 0, stream>>>(xyzp, new_xyz, feats, idx_dn, td_w0, td_b0, act0);
  bn_reduce_kernel<<<64, 256, 0, stream>>>(act0, sums0);
  bn_finalize_kernel<<<1, 128, 0, stream>>>(sums0, bn0_g, bn0_b, sc0, sh0);
  td1_kernel<<<B * S * K, 128, 0, stream>>>(act0, sc0, sh0, td_w1, td_b1, act1);
  bn_reduce_kernel<<<64, 256, 0, stream>>>(act1, sums1);
  bn_finalize_kernel<<<1, 128, 0, stream>>>(sums1, bn1_g, bn1_b, sc1, sh1);
  maxpool_kernel<<<B * S, 128, 0, stream>>>(act1, sc1, sh1, new_feats);
  rowgemm_kernel<<<B * S, 128, 0, stream>>>(new_feats, w_gkern, b_gkern, new_x);
  kv_kernel<<<B * S, 128, 0, stream>>>(new_x, w_k, w_v, kk, vv);
  q_kernel<<<B * N, 128, 0, stream>>>(feats, w_kern, b_kern, w_q, q);
  attn_kernel<<<B * N, 128, 0, stream>>>(xyzp, q, kk, vv, new_xyzp, idx_up, feats,
      pe_w1, pe_b1, pe_w2, pe_b2, at_w1, at_b1, at_w2, at_b2, w_agg, b_agg, out);
}

// Round 3
// 3593.815 us; speedup vs baseline: 1.5068x; 1.5068x over previous
//
#include <hip/hip_runtime.h>

constexpr int B = 4, N = 8192, S = 512, K = 16, F = 128, H = 128;
constexpr float EPS = 1e-5f;

// ---------------------------------------------------------------- layernorm
__global__ __launch_bounds__(128) void ln_kernel(const float* __restrict__ features,
    const float* __restrict__ g, const float* __restrict__ bta, float* __restrict__ feats) {
  int r = blockIdx.x, t = threadIdx.x;
  __shared__ float red[128];
  float v = features[(size_t)r * F + t];
  red[t] = v; __syncthreads();
  #pragma unroll
  for (int off = 64; off > 0; off >>= 1) { if (t < off) red[t] += red[t + off]; __syncthreads(); }
  float m = red[0] * (1.f / F);
  __syncthreads();
  float d = v - m;
  red[t] = d * d; __syncthreads();
  #pragma unroll
  for (int off = 64; off > 0; off >>= 1) { if (t < off) red[t] += red[t + off]; __syncthreads(); }
  float var = red[0] * (1.f / F);
  float rstd = rsqrtf(var + EPS);
  feats[(size_t)r * F + t] = d * rstd * g[t] + bta[t];
}

// ---------------------------------------------------------------- FPS (sequential, 1 block per batch)
__global__ __launch_bounds__(1024) void fps_kernel(const float* __restrict__ xyzp,
    int* __restrict__ fps_idx, float* __restrict__ new_xyz) {
  int b = blockIdx.x, t = threadIdx.x;
  const float4* xp = (const float4*)(xyzp + (size_t)b * N * 4);
  float px[8], py[8], pz[8], mind[8];
  #pragma unroll
  for (int j = 0; j < 8; j++) {
    float4 p = xp[t + 1024 * j];
    px[j] = p.x; py[j] = p.y; pz[j] = p.z;
    mind[j] = 1e10f;
  }
  __shared__ float wval[16];
  __shared__ int widx[16];
  __shared__ int s_last;
  int last = 0;
  if (t == 0) fps_idx[b * S] = 0;
  if (t == 0) {
    float4 p0 = xp[0];
    new_xyz[((size_t)b * S) * 3 + 0] = p0.x;
    new_xyz[((size_t)b * S) * 3 + 1] = p0.y;
    new_xyz[((size_t)b * S) * 3 + 2] = p0.z;
  }
  for (int s = 1; s < S; ++s) {
    float4 lp = xp[last];
    float lx = lp.x, ly = lp.y, lz = lp.z;
    float bv = -1.f; int bi = 0;
    #pragma unroll
    for (int j = 0; j < 8; j++) {
      float dx = __fsub_rn(px[j], lx), dy = __fsub_rn(py[j], ly), dz = __fsub_rn(pz[j], lz);
      float d = __fadd_rn(__fadd_rn(__fmul_rn(dx, dx), __fmul_rn(dy, dy)), __fmul_rn(dz, dz));
      mind[j] = fminf(mind[j], d);
      if (mind[j] > bv) { bv = mind[j]; bi = t + 1024 * j; }   // strict > : lowest idx in-lane on tie
    }
    #pragma unroll
    for (int off = 32; off > 0; off >>= 1) {
      float ov = __shfl_down(bv, off); int oi = __shfl_down(bi, off);
      if (ov > bv || (ov == bv && oi < bi)) { bv = ov; bi = oi; }
    }
    int wid = t >> 6, lane = t & 63;
    if (lane == 0) { wval[wid] = bv; widx[wid] = bi; }
    __syncthreads();
    if (t == 0) {
      float v = wval[0]; int i = widx[0];
      for (int w = 1; w < 16; w++) {
        float ov = wval[w]; int oi = widx[w];
        if (ov > v || (ov == v && oi < i)) { v = ov; i = oi; }
      }
      s_last = i; fps_idx[b * S + s] = i;
      float4 p = xp[i];
      new_xyz[((size_t)b * S + s) * 3 + 0] = p.x;
      new_xyz[((size_t)b * S + s) * 3 + 1] = p.y;
      new_xyz[((size_t)b * S + s) * 3 + 2] = p.z;
    }
    __syncthreads();
    last = s_last;
  }
}

// ---------------------------------------------------------------- kNN: 512 queries vs 8192 refs
// One wave per query. Each lane owns refs {lane + 64j}. Per-lane state is only
// (curD,curI,lastD,lastI) scalars -> no arrays, no scratch. 16 extraction
// rounds of wave-argmin; winner lane rescans its 128-ref slice (exec-masked).
// Produces top-16 in exact ascending (d2, idx) order == lax.top_k semantics.
__global__ __launch_bounds__(256) void knn_dn_kernel(const float* __restrict__ xyzp,
    const float* __restrict__ new_xyz, int* __restrict__ idx_dn, float* __restrict__ new_xyzp) {
  int wave = threadIdx.x >> 6, lane = threadIdx.x & 63;
  int qid = blockIdx.x * 4 + wave;         // 0 .. 2047
  int b = qid >> 9, s = qid & (S - 1);
  const float4* xp = (const float4*)(xyzp + (size_t)b * N * 4);
  float qx = new_xyz[((size_t)b * S + s) * 3 + 0];
  float qy = new_xyz[((size_t)b * S + s) * 3 + 1];
  float qz = new_xyz[((size_t)b * S + s) * 3 + 2];
  float qq = __fadd_rn(__fadd_rn(__fmul_rn(qx, qx), __fmul_rn(qy, qy)), __fmul_rn(qz, qz));

  float lastD = -1.f; int lastI = -1;
  float curD; int curI;
  // scan: min over slice of keys (d2,i) lexicographically > (lastD,lastI)
  auto scan = [&]() {
    curD = 3e38f; curI = 0x7fffffff;
    for (int j = 0; j < 128; j++) {
      int i = lane + 64 * j;
      float4 p = xp[i];
      float rr  = __fadd_rn(__fadd_rn(__fmul_rn(p.x, p.x), __fmul_rn(p.y, p.y)), __fmul_rn(p.z, p.z));
      float dot = __fadd_rn(__fadd_rn(__fmul_rn(qx, p.x), __fmul_rn(qy, p.y)), __fmul_rn(qz, p.z));
      float d2 = __fsub_rn(__fadd_rn(qq, rr), __fmul_rn(2.0f, dot));
      bool gate   = (d2 > lastD) || (d2 == lastD && i > lastI);
      bool better = (d2 < curD) || (d2 == curD && i < curI);
      if (gate && better) { curD = d2; curI = i; }
    }
  };
  scan();
  int outI = 0;
  float4 nn0;
  #pragma unroll 1
  for (int r = 0; r < K; r++) {
    float mD = curD; int mI = curI; int mL = lane;
    #pragma unroll
    for (int off = 32; off > 0; off >>= 1) {
      float od = __shfl_xor(mD, off); int oi = __shfl_xor(mI, off); int ol = __shfl_xor(mL, off);
      if (od < mD || (od == mD && oi < mI)) { mD = od; mI = oi; mL = ol; }
    }
    if (lane == r) outI = mI;
    if (r == 0 && lane == 0) nn0 = xp[mI];
    if (lane == mL) { lastD = mD; lastI = mI; scan(); }
  }
  size_t base = ((size_t)b * S + s) * K;
  if (lane < K) idx_dn[base + lane] = outI;
  if (lane == 0) *(float4*)&new_xyzp[((size_t)b * S + s) * 4] = nn0;
}

// ---------------------------------------------------------------- kNN: 8192 queries vs 512 refs
// Same wave-per-query scheme; each lane's 8 refs live fully in registers.
__global__ __launch_bounds__(256) void knn_up_kernel(const float* __restrict__ xyzp,
    const float* __restrict__ new_xyz, int* __restrict__ idx_up) {
  int wave = threadIdx.x >> 6, lane = threadIdx.x & 63;
  int qid = blockIdx.x * 4 + wave;         // 0 .. 32767
  int b = qid >> 13, n = qid & (N - 1);
  const float4* xp = (const float4*)(xyzp + (size_t)b * N * 4);
  float4 qp = xp[n];
  float qx = qp.x, qy = qp.y, qz = qp.z;
  float qq = __fadd_rn(__fadd_rn(__fmul_rn(qx, qx), __fmul_rn(qy, qy)), __fmul_rn(qz, qz));
  float rx[8], ry[8], rz[8];
  #pragma unroll
  for (int j = 0; j < 8; j++) {
    int i = lane + 64 * j;
    rx[j] = new_xyz[((size_t)b * S + i) * 3 + 0];
    ry[j] = new_xyz[((size_t)b * S + i) * 3 + 1];
    rz[j] = new_xyz[((size_t)b * S + i) * 3 + 2];
  }
  float lastD = -1.f; int lastI = -1;
  float curD; int curI;
  auto scan = [&]() {
    curD = 3e38f; curI = 0x7fffffff;
    #pragma unroll
    for (int j = 0; j < 8; j++) {
      int i = lane + 64 * j;
      float rr  = __fadd_rn(__fadd_rn(__fmul_rn(rx[j], rx[j]), __fmul_rn(ry[j], ry[j])), __fmul_rn(rz[j], rz[j]));
      float dot = __fadd_rn(__fadd_rn(__fmul_rn(qx, rx[j]), __fmul_rn(qy, ry[j])), __fmul_rn(qz, rz[j]));
      float d2 = __fsub_rn(__fadd_rn(qq, rr), __fmul_rn(2.0f, dot));
      bool gate   = (d2 > lastD) || (d2 == lastD && i > lastI);
      bool better = (d2 < curD) || (d2 == curD && i < curI);
      if (gate && better) { curD = d2; curI = i; }
    }
  };
  scan();
  int outI = 0;
  #pragma unroll 1
  for (int r = 0; r < K; r++) {
    float mD = curD; int mI = curI; int mL = lane;
    #pragma unroll
    for (int off = 32; off > 0; off >>= 1) {
      float od = __shfl_xor(mD, off); int oi = __shfl_xor(mI, off); int ol = __shfl_xor(mL, off);
      if (od < mD || (od == mD && oi < mI)) { mD = od; mI = oi; mL = ol; }
    }
    if (lane == r) outI = mI;
    if (lane == mL) { lastD = mD; lastI = mI; scan(); }
  }
  size_t base = ((size_t)b * N + n) * K;
  if (lane < K) idx_up[base + lane] = outI;
}

// ---------------------------------------------------------------- grouped MLP layer 0 (131 -> 128)
__global__ __launch_bounds__(128) void td0_kernel(const float* __restrict__ xyzp,
    const float* __restrict__ new_xyz, const float* __restrict__ feats,
    const int* __restrict__ idx_dn, const float* __restrict__ w0, const float* __restrict__ b0,
    float* __restrict__ act0) {
  int rowid = blockIdx.x, t = threadIdx.x;
  int b = rowid >> 13;
  int s = (rowid >> 4) & (S - 1);
  __shared__ float row[131];
  int idxn = idx_dn[rowid];
  if (t < 3) row[t] = xyzp[((size_t)b * N + idxn) * 4 + t] - new_xyz[((size_t)b * S + s) * 3 + t];
  row[3 + t] = feats[((size_t)b * N + idxn) * F + t];
  __syncthreads();
  float acc = b0[t];
  for (int i = 0; i < 131; i++) acc = fmaf(row[i], w0[i * F + t], acc);
  act0[(size_t)rowid * F + t] = acc;
}

// ---------------------------------------------------------------- batchnorm stats
__global__ __launch_bounds__(256) void bn_reduce_kernel(const float* __restrict__ x,
                                                        float* __restrict__ sums) {
  __shared__ float ls[256], ls2[256];
  int t = threadIdx.x;
  size_t base = (size_t)blockIdx.x * 65536 + t;
  float s = 0.f, s2 = 0.f;
  for (int i = 0; i < 256; i++) {
    float v = x[base + (size_t)i * 256];
    s += v; s2 = fmaf(v, v, s2);
  }
  ls[t] = s; ls2[t] = s2; __syncthreads();
  if (t < 128) {
    s = ls[t] + ls[t + 128]; s2 = ls2[t] + ls2[t + 128];
    atomicAdd(&sums[t], s); atomicAdd(&sums[128 + t], s2);
  }
}

__global__ void bn_finalize_kernel(const float* __restrict__ sums, const float* __restrict__ g,
    const float* __restrict__ bta, float* __restrict__ scale, float* __restrict__ shift) {
  int t = threadIdx.x;
  float m = sums[t] * (1.f / 32768.f);
  float var = sums[128 + t] * (1.f / 32768.f) - m * m;
  float rstd = rsqrtf(var + EPS);
  float sc = g[t] * rstd;
  scale[t] = sc;
  shift[t] = bta[t] - m * sc;
}

// ---------------------------------------------------------------- grouped MLP layer 1 (128 -> 128)
__global__ __launch_bounds__(128) void td1_kernel(const float* __restrict__ act0,
    const float* __restrict__ scale, const float* __restrict__ shift,
    const float* __restrict__ w1, const float* __restrict__ b1, float* __restrict__ act1) {
  int rowid = blockIdx.x, t = threadIdx.x;
  __shared__ float row[128];
  float xn = fmaxf(fmaf(act0[(size_t)rowid * F + t], scale[t], shift[t]), 0.f);
  row[t] = xn; __syncthreads();
  float acc = b1[t];
  for (int i = 0; i < F; i++) acc = fmaf(row[i], w1[i * F + t], acc);
  act1[(size_t)rowid * F + t] = acc;
}

// ---------------------------------------------------------------- BN+relu+max over K
__global__ __launch_bounds__(128) void maxpool_kernel(const float* __restrict__ act1,
    const float* __restrict__ scale, const float* __restrict__ shift, float* __restrict__ new_feats) {
  int bs = blockIdx.x, t = threadIdx.x;
  float sc = scale[t], sh = shift[t];
  float m = -3e38f;
  for (int k = 0; k < K; k++) {
    float v = fmaxf(fmaf(act1[((size_t)bs * K + k) * F + t], sc, sh), 0.f);
    m = fmaxf(m, v);
  }
  new_feats[(size_t)bs * F + t] = m;
}

// ---------------------------------------------------------------- new_x = new_feats @ w_gkern + b
__global__ __launch_bounds__(128) void rowgemm_kernel(const float* __restrict__ in,
    const float* __restrict__ w, const float* __restrict__ bias, float* __restrict__ out) {
  int r = blockIdx.x, t = threadIdx.x;
  __shared__ float row[128];
  row[t] = in[(size_t)r * F + t]; __syncthreads();
  float acc = bias[t];
  for (int i = 0; i < F; i++) acc = fmaf(row[i], w[i * F + t], acc);
  out[(size_t)r * F + t] = acc;
}

// ---------------------------------------------------------------- kk/vv = new_x @ w_k / w_v
__global__ __launch_bounds__(128) void kv_kernel(const float* __restrict__ new_x,
    const float* __restrict__ wk, const float* __restrict__ wvp,
    float* __restrict__ kk, float* __restrict__ vv) {
  int r = blockIdx.x, t = threadIdx.x;
  __shared__ float row[128];
  row[t] = new_x[(size_t)r * F + t]; __syncthreads();
  float ak = 0.f, av = 0.f;
  for (int i = 0; i < F; i++) {
    float x = row[i];
    ak = fmaf(x, wk[i * F + t], ak);
    av = fmaf(x, wvp[i * F + t], av);
  }
  kk[(size_t)r * F + t] = ak;
  vv[(size_t)r * F + t] = av;
}

// ---------------------------------------------------------------- q = (feats @ w_kern + b) @ w_q
__global__ __launch_bounds__(128) void q_kernel(const float* __restrict__ feats,
    const float* __restrict__ w_kern, const float* __restrict__ b_kern,
    const float* __restrict__ w_q, float* __restrict__ q) {
  int r = blockIdx.x, t = threadIdx.x;
  __shared__ float row[128], row2[128];
  row[t] = feats[(size_t)r * F + t]; __syncthreads();
  float acc = b_kern[t];
  for (int i = 0; i < F; i++) acc = fmaf(row[i], w_kern[i * F + t], acc);
  row2[t] = acc; __syncthreads();
  float aq = 0.f;
  for (int i = 0; i < F; i++) aq = fmaf(row2[i], w_q[i * F + t], aq);
  q[(size_t)r * F + t] = aq;
}

// ---------------------------------------------------------------- fused neighbor attention + epilogue
__global__ __launch_bounds__(128) void attn_kernel(const float* __restrict__ xyzp,
    const float* __restrict__ q, const float* __restrict__ kk, const float* __restrict__ vv,
    const float* __restrict__ new_xyzp, const int* __restrict__ idx_up,
    const float* __restrict__ feats,
    const float* __restrict__ pe_w1, const float* __restrict__ pe_b1,
    const float* __restrict__ pe_w2, const float* __restrict__ pe_b2,
    const float* __restrict__ at_w1, const float* __restrict__ at_b1,
    const float* __restrict__ at_w2, const float* __restrict__ at_b2,
    const float* __restrict__ w_agg, const float* __restrict__ b_agg,
    float* __restrict__ out) {
  int p = blockIdx.x, t = threadIdx.x;
  int b = p >> 13;
  __shared__ float qs[128];
  __shared__ float pd[16][4];
  __shared__ int nb[16];
  __shared__ __align__(16) float buf1[16][128];   // peh, then tact
  __shared__ __align__(16) float av[16][128];
  __shared__ __align__(16) float wv[16][128];
  qs[t] = q[(size_t)p * H + t];
  if (t < 16) nb[t] = idx_up[(size_t)p * K + t];
  __syncthreads();
  if (t < 64) {
    int k = t >> 2, d = t & 3;
    pd[k][d] = xyzp[(size_t)p * 4 + d] - new_xyzp[((size_t)b * S + nb[k]) * 4 + d];
  }
  __syncthreads();
  { // pe layer 1: 4 -> 128, relu
    float bb = pe_b1[t];
    float w0 = pe_w1[0 * H + t], w1 = pe_w1[1 * H + t];
    float w2 = pe_w1[2 * H + t], w3 = pe_w1[3 * H + t];
    #pragma unroll
    for (int k = 0; k < 16; k++) {
      float h = bb + pd[k][0] * w0 + pd[k][1] * w1 + pd[k][2] * w2 + pd[k][3] * w3;
      buf1[k][t] = fmaxf(h, 0.f);
    }
  }
  __syncthreads();
  { // pe layer 2 -> pos_enc; build av / wv
    float acc[16];
    float bb = pe_b2[t];
    #pragma unroll
    for (int k = 0; k < 16; k++) acc[k] = bb;
    for (int i4 = 0; i4 < H / 4; i4++) {
      int i = i4 * 4;
      float w0 = pe_w2[(i + 0) * H + t], w1 = pe_w2[(i + 1) * H + t];
      float w2 = pe_w2[(i + 2) * H + t], w3 = pe_w2[(i + 3) * H + t];
      #pragma unroll
      for (int k = 0; k < 16; k++) {
        float4 x = *(const float4*)&buf1[k][i];
        acc[k] = fmaf(x.x, w0, acc[k]); acc[k] = fmaf(x.y, w1, acc[k]);
        acc[k] = fmaf(x.z, w2, acc[k]); acc[k] = fmaf(x.w, w3, acc[k]);
      }
    }
    #pragma unroll
    for (int k = 0; k < 16; k++) {
      int s = nb[k];
      float kkv = kk[((size_t)b * S + s) * H + t];
      float vvv = vv[((size_t)b * S + s) * H + t];
      av[k][t] = qs[t] - kkv + acc[k];
      wv[k][t] = vvv + acc[k];
    }
  }
  __syncthreads();
  { // attn MLP layer 1: relu(av @ at_w1 + b) -> buf1
    float acc[16];
    float bb = at_b1[t];
    #pragma unroll
    for (int k = 0; k < 16; k++) acc[k] = bb;
    for (int i4 = 0; i4 < H / 4; i4++) {
      int i = i4 * 4;
      float w0 = at_w1[(i + 0) * H + t], w1 = at_w1[(i + 1) * H + t];
      float w2 = at_w1[(i + 2) * H + t], w3 = at_w1[(i + 3) * H + t];
      #pragma unroll
      for (int k = 0; k < 16; k++) {
        float4 x = *(const float4*)&av[k][i];
        acc[k] = fmaf(x.x, w0, acc[k]); acc[k] = fmaf(x.y, w1, acc[k]);
        acc[k] = fmaf(x.z, w2, acc[k]); acc[k] = fmaf(x.w, w3, acc[k]);
      }
    }
    #pragma unroll
    for (int k = 0; k < 16; k++) buf1[k][t] = fmaxf(acc[k], 0.f);
  }
  __syncthreads();
  float lg[16];
  { // attn MLP layer 2 -> logits (kept in registers, per channel)
    float bb = at_b2[t];
    #pragma unroll
    for (int k = 0; k < 16; k++) lg[k] = bb;
    for (int i4 = 0; i4 < H / 4; i4++) {
      int i = i4 * 4;
      float w0 = at_w2[(i + 0) * H + t], w1 = at_w2[(i + 1) * H + t];
      float w2 = at_w2[(i + 2) * H + t], w3 = at_w2[(i + 3) * H + t];
      #pragma unroll
      for (int k = 0; k < 16; k++) {
        float4 x = *(const float4*)&buf1[k][i];
        lg[k] = fmaf(x.x, w0, lg[k]); lg[k] = fmaf(x.y, w1, lg[k]);
        lg[k] = fmaf(x.z, w2, lg[k]); lg[k] = fmaf(x.w, w3, lg[k]);
      }
    }
  }
  float res = 0.f;
  { // per-channel softmax over the 16 neighbors (all in registers)
    float m = -3e38f;
    #pragma unroll
    for (int k = 0; k < 16; k++) { lg[k] = lg[k] / 11.3137085f; m = fmaxf(m, lg[k]); }
    float sum = 0.f;
    #pragma unroll
    for (int k = 0; k < 16; k++) { lg[k] = expf(lg[k] - m); sum += lg[k]; }
    float inv = 1.f / sum;
    #pragma unroll
    for (int k = 0; k < 16; k++) res = fmaf(lg[k] * inv, wv[k][t], res);
  }
  __syncthreads();
  qs[t] = res;
  __syncthreads();
  float o = b_agg[t];
  for (int i = 0; i < H; i++) o = fmaf(qs[i], w_agg[i * H + t], o);
  o += feats[(size_t)p * F + t];
  out[(size_t)p * F + t] = o;
}

// ================================================================ host
extern "C" void kernel_launch(void* const* d_in, const int* in_sizes, int n_in,
                              void* d_out, int out_size, void* d_ws, size_t ws_size,
                              hipStream_t stream) {
  (void)in_sizes; (void)n_in; (void)out_size; (void)ws_size;
  const float* xyzp    = (const float*)d_in[0];
  const float* features= (const float*)d_in[1];
  const float* ln_g    = (const float*)d_in[2];
  const float* ln_b    = (const float*)d_in[3];
  const float* td_w0   = (const float*)d_in[4];
  const float* td_b0   = (const float*)d_in[5];
  const float* bn0_g   = (const float*)d_in[6];
  const float* bn0_b   = (const float*)d_in[7];
  const float* td_w1   = (const float*)d_in[8];
  const float* td_b1   = (const float*)d_in[9];
  const float* bn1_g   = (const float*)d_in[10];
  const float* bn1_b   = (const float*)d_in[11];
  const float* w_kern  = (const float*)d_in[12];
  const float* b_kern  = (const float*)d_in[13];
  const float* w_gkern = (const float*)d_in[14];
  const float* b_gkern = (const float*)d_in[15];
  const float* w_agg   = (const float*)d_in[16];
  const float* b_agg   = (const float*)d_in[17];
  const float* w_q     = (const float*)d_in[18];
  const float* w_k     = (const float*)d_in[19];
  const float* w_v     = (const float*)d_in[20];
  const float* pe_w1   = (const float*)d_in[21];
  const float* pe_b1   = (const float*)d_in[22];
  const float* pe_w2   = (const float*)d_in[23];
  const float* pe_b2   = (const float*)d_in[24];
  const float* at_w1   = (const float*)d_in[25];
  const float* at_b1   = (const float*)d_in[26];
  const float* at_w2   = (const float*)d_in[27];
  const float* at_b2   = (const float*)d_in[28];
  float* out = (float*)d_out;

  float* wsf = (float*)d_ws;
  float* feats     = wsf + 0;           // 4194304
  float* q         = wsf + 4194304;     // 4194304
  float* act0      = wsf + 8388608;     // 4194304
  float* act1      = wsf + 12582912;    // 4194304
  float* new_feats = wsf + 16777216;    // 262144
  float* new_x     = wsf + 17039360;    // 262144
  float* kk        = wsf + 17301504;    // 262144
  float* vv        = wsf + 17563648;    // 262144
  float* new_xyz   = wsf + 17825792;    // 6144
  float* new_xyzp  = wsf + 17831936;    // 8192
  float* sums0     = wsf + 17840128;    // 256
  float* sums1     = wsf + 17840384;    // 256
  float* sc0       = wsf + 17840640;    // 128
  float* sh0       = wsf + 17840768;    // 128
  float* sc1       = wsf + 17840896;    // 128
  float* sh1       = wsf + 17841024;    // 128
  int* fps_idx = (int*)(wsf + 17841152);
  int* idx_dn  = fps_idx + 2048;
  int* idx_up  = idx_dn + 32768;

  hipMemsetAsync(sums0, 0, 512 * sizeof(float), stream);
  ln_kernel<<<B * N, 128, 0, stream>>>(features, ln_g, ln_b, feats);
  fps_kernel<<<B, 1024, 0, stream>>>(xyzp, fps_idx, new_xyz);
  knn_dn_kernel<<<512, 256, 0, stream>>>(xyzp, new_xyz, idx_dn, new_xyzp);
  knn_up_kernel<<<8192, 256, 0, stream>>>(xyzp, new_xyz, idx_up);
  td0_kernel<<<B * S * K, 128, 0, stream>>>(xyzp, new_xyz, feats, idx_dn, td_w0, td_b0, act0);
  bn_reduce_kernel<<<64, 256, 0, stream>>>(act0, sums0);
  bn_finalize_kernel<<<1, 128, 0, stream>>>(sums0, bn0_g, bn0_b, sc0, sh0);
  td1_kernel<<<B * S * K, 128, 0, stream>>>(act0, sc0, sh0, td_w1, td_b1, act1);
  bn_reduce_kernel<<<64, 256, 0, stream>>>(act1, sums1);
  bn_finalize_kernel<<<1, 128, 0, stream>>>(sums1, bn1_g, bn1_b, sc1, sh1);
  maxpool_kernel<<<B * S, 128, 0, stream>>>(act1, sc1, sh1, new_feats);
  rowgemm_kernel<<<B * S, 128, 0, stream>>>(new_feats, w_gkern, b_gkern, new_x);
  kv_kernel<<<B * S, 128, 0, stream>>>(new_x, w_k, w_v, kk, vv);
  q_kernel<<<B * N, 128, 0, stream>>>(feats, w_kern, b_kern, w_q, q);
  attn_kernel<<<B * N, 128, 0, stream>>>(xyzp, q, kk, vv, new_xyzp, idx_up, feats,
      pe_w1, pe_b1, pe_w2, pe_b2, at_w1, at_b1, at_w2, at_b2, w_agg, b_agg, out);
}

// Round 4
// 2426.143 us; speedup vs baseline: 2.2321x; 1.4813x over previous
//
#include <hip/hip_runtime.h>

constexpr int B = 4, N = 8192, S = 512, K = 16, F = 128, H = 128;
constexpr float EPS = 1e-5f;

typedef short v8s __attribute__((ext_vector_type(8)));
typedef float v4f __attribute__((ext_vector_type(4)));

__device__ __forceinline__ short f2bf(float x) {
  union { float f; unsigned u; } v; v.f = x;
  unsigned r = v.u + 0x7fffu + ((v.u >> 16) & 1u);   // RNE
  return (short)(r >> 16);
}
__device__ __forceinline__ float bf2f(short s) {
  union { unsigned u; float f; } v; v.u = ((unsigned)(unsigned short)s) << 16;
  return v.f;
}

// ---------------------------------------------------------------- layernorm
__global__ __launch_bounds__(128) void ln_kernel(const float* __restrict__ features,
    const float* __restrict__ g, const float* __restrict__ bta, float* __restrict__ feats) {
  int r = blockIdx.x, t = threadIdx.x;
  __shared__ float red[128];
  float v = features[(size_t)r * F + t];
  red[t] = v; __syncthreads();
  #pragma unroll
  for (int off = 64; off > 0; off >>= 1) { if (t < off) red[t] += red[t + off]; __syncthreads(); }
  float m = red[0] * (1.f / F);
  __syncthreads();
  float d = v - m;
  red[t] = d * d; __syncthreads();
  #pragma unroll
  for (int off = 64; off > 0; off >>= 1) { if (t < off) red[t] += red[t + off]; __syncthreads(); }
  float var = red[0] * (1.f / F);
  float rstd = rsqrtf(var + EPS);
  feats[(size_t)r * F + t] = d * rstd * g[t] + bta[t];
}

// ---------------------------------------------------------------- FPS
// Winner coords published from the owning thread's REGISTERS via LDS — no
// global load in the serial dependency chain. 16-entry cross-wave reduce via
// shfl butterfly instead of a serial t0 scan. 3 barriers/step.
__global__ __launch_bounds__(1024) void fps_kernel(const float* __restrict__ xyzp,
    float* __restrict__ new_xyz) {
  int b = blockIdx.x, t = threadIdx.x;
  const float4* xp = (const float4*)(xyzp + (size_t)b * N * 4);
  float px[8], py[8], pz[8], mind[8];
  #pragma unroll
  for (int j = 0; j < 8; j++) {
    float4 p = xp[t + 1024 * j];
    px[j] = p.x; py[j] = p.y; pz[j] = p.z;
    mind[j] = 1e10f;
  }
  __shared__ float wval[16];
  __shared__ int   widx[16];
  __shared__ int   s_win;
  __shared__ float s_px, s_py, s_pz;
  if (t == 0) {
    float4 p0 = xp[0];
    s_px = p0.x; s_py = p0.y; s_pz = p0.z;
    new_xyz[(size_t)b * S * 3 + 0] = p0.x;
    new_xyz[(size_t)b * S * 3 + 1] = p0.y;
    new_xyz[(size_t)b * S * 3 + 2] = p0.z;
  }
  __syncthreads();
  int lane = t & 63, wid = t >> 6;
  for (int s = 1; s < S; ++s) {
    float lx = s_px, ly = s_py, lz = s_pz;
    float bv = -1.f; int bi = 0;
    #pragma unroll
    for (int j = 0; j < 8; j++) {
      float dx = __fsub_rn(px[j], lx), dy = __fsub_rn(py[j], ly), dz = __fsub_rn(pz[j], lz);
      float d = __fadd_rn(__fadd_rn(__fmul_rn(dx, dx), __fmul_rn(dy, dy)), __fmul_rn(dz, dz));
      mind[j] = fminf(mind[j], d);
      if (mind[j] > bv) { bv = mind[j]; bi = t + 1024 * j; }  // j asc -> lowest idx on tie
    }
    #pragma unroll
    for (int off = 32; off > 0; off >>= 1) {
      float ov = __shfl_down(bv, off); int oi = __shfl_down(bi, off);
      if (ov > bv || (ov == bv && oi < bi)) { bv = ov; bi = oi; }
    }
    if (lane == 0) { wval[wid] = bv; widx[wid] = bi; }
    __syncthreads();
    if (t < 16) {
      float v = wval[t]; int i = widx[t];
      #pragma unroll
      for (int off = 8; off > 0; off >>= 1) {
        float ov = __shfl_xor(v, off); int oi = __shfl_xor(i, off);
        if (ov > v || (ov == v && oi < i)) { v = ov; i = oi; }
      }
      if (t == 0) s_win = i;
    }
    __syncthreads();
    int win = s_win;
    if ((win & 1023) == t) {
      int j = win >> 10;
      s_px = px[j]; s_py = py[j]; s_pz = pz[j];
      new_xyz[((size_t)b * S + s) * 3 + 0] = px[j];
      new_xyz[((size_t)b * S + s) * 3 + 1] = py[j];
      new_xyz[((size_t)b * S + s) * 3 + 2] = pz[j];
    }
    __syncthreads();
  }
}

// ---------------------------------------------------------------- kNN: 512 queries vs 8192 refs
__global__ __launch_bounds__(256) void knn_dn_kernel(const float* __restrict__ xyzp,
    const float* __restrict__ new_xyz, int* __restrict__ idx_dn, float* __restrict__ new_xyzp) {
  int wave = threadIdx.x >> 6, lane = threadIdx.x & 63;
  int qid = blockIdx.x * 4 + wave;
  int b = qid >> 9, s = qid & (S - 1);
  const float4* xp = (const float4*)(xyzp + (size_t)b * N * 4);
  float qx = new_xyz[((size_t)b * S + s) * 3 + 0];
  float qy = new_xyz[((size_t)b * S + s) * 3 + 1];
  float qz = new_xyz[((size_t)b * S + s) * 3 + 2];
  float qq = __fadd_rn(__fadd_rn(__fmul_rn(qx, qx), __fmul_rn(qy, qy)), __fmul_rn(qz, qz));

  float lastD = -1.f; int lastI = -1;
  float curD; int curI;
  auto scan = [&]() {
    curD = 3e38f; curI = 0x7fffffff;
    for (int j = 0; j < 128; j++) {
      int i = lane + 64 * j;
      float4 p = xp[i];
      float rr  = __fadd_rn(__fadd_rn(__fmul_rn(p.x, p.x), __fmul_rn(p.y, p.y)), __fmul_rn(p.z, p.z));
      float dot = __fadd_rn(__fadd_rn(__fmul_rn(qx, p.x), __fmul_rn(qy, p.y)), __fmul_rn(qz, p.z));
      float d2 = __fsub_rn(__fadd_rn(qq, rr), __fmul_rn(2.0f, dot));
      bool gate   = (d2 > lastD) || (d2 == lastD && i > lastI);
      bool better = (d2 < curD) || (d2 == curD && i < curI);
      if (gate && better) { curD = d2; curI = i; }
    }
  };
  scan();
  int outI = 0;
  float4 nn0;
  #pragma unroll 1
  for (int r = 0; r < K; r++) {
    float mD = curD; int mI = curI; int mL = lane;
    #pragma unroll
    for (int off = 32; off > 0; off >>= 1) {
      float od = __shfl_xor(mD, off); int oi = __shfl_xor(mI, off); int ol = __shfl_xor(mL, off);
      if (od < mD || (od == mD && oi < mI)) { mD = od; mI = oi; mL = ol; }
    }
    if (lane == r) outI = mI;
    if (r == 0 && lane == 0) nn0 = xp[mI];
    if (lane == mL) { lastD = mD; lastI = mI; scan(); }
  }
  size_t base = ((size_t)b * S + s) * K;
  if (lane < K) idx_dn[base + lane] = outI;
  if (lane == 0) *(float4*)&new_xyzp[((size_t)b * S + s) * 4] = nn0;
}

// ---------------------------------------------------------------- kNN: 8192 queries vs 512 refs
__global__ __launch_bounds__(256) void knn_up_kernel(const float* __restrict__ xyzp,
    const float* __restrict__ new_xyz, int* __restrict__ idx_up) {
  int wave = threadIdx.x >> 6, lane = threadIdx.x & 63;
  int qid = blockIdx.x * 4 + wave;
  int b = qid >> 13, n = qid & (N - 1);
  const float4* xp = (const float4*)(xyzp + (size_t)b * N * 4);
  float4 qp = xp[n];
  float qx = qp.x, qy = qp.y, qz = qp.z;
  float qq = __fadd_rn(__fadd_rn(__fmul_rn(qx, qx), __fmul_rn(qy, qy)), __fmul_rn(qz, qz));
  float rx[8], ry[8], rz[8];
  #pragma unroll
  for (int j = 0; j < 8; j++) {
    int i = lane + 64 * j;
    rx[j] = new_xyz[((size_t)b * S + i) * 3 + 0];
    ry[j] = new_xyz[((size_t)b * S + i) * 3 + 1];
    rz[j] = new_xyz[((size_t)b * S + i) * 3 + 2];
  }
  float lastD = -1.f; int lastI = -1;
  float curD; int curI;
  auto scan = [&]() {
    curD = 3e38f; curI = 0x7fffffff;
    #pragma unroll
    for (int j = 0; j < 8; j++) {
      int i = lane + 64 * j;
      float rr  = __fadd_rn(__fadd_rn(__fmul_rn(rx[j], rx[j]), __fmul_rn(ry[j], ry[j])), __fmul_rn(rz[j], rz[j]));
      float dot = __fadd_rn(__fadd_rn(__fmul_rn(qx, rx[j]), __fmul_rn(qy, ry[j])), __fmul_rn(qz, rz[j]));
      float d2 = __fsub_rn(__fadd_rn(qq, rr), __fmul_rn(2.0f, dot));
      bool gate   = (d2 > lastD) || (d2 == lastD && i > lastI);
      bool better = (d2 < curD) || (d2 == curD && i < curI);
      if (gate && better) { curD = d2; curI = i; }
    }
  };
  scan();
  int outI = 0;
  #pragma unroll 1
  for (int r = 0; r < K; r++) {
    float mD = curD; int mI = curI; int mL = lane;
    #pragma unroll
    for (int off = 32; off > 0; off >>= 1) {
      float od = __shfl_xor(mD, off); int oi = __shfl_xor(mI, off); int ol = __shfl_xor(mL, off);
      if (od < mD || (od == mD && oi < mI)) { mD = od; mI = oi; mL = ol; }
    }
    if (lane == r) outI = mI;
    if (lane == mL) { lastD = mD; lastI = mI; scan(); }
  }
  size_t base = ((size_t)b * N + n) * K;
  if (lane < K) idx_up[base + lane] = outI;
}

// ---------------------------------------------------------------- grouped MLP layer 0 (131 -> 128)
__global__ __launch_bounds__(128) void td0_kernel(const float* __restrict__ xyzp,
    const float* __restrict__ new_xyz, const float* __restrict__ feats,
    const int* __restrict__ idx_dn, const float* __restrict__ w0, const float* __restrict__ b0,
    float* __restrict__ act0) {
  int rowid = blockIdx.x, t = threadIdx.x;
  int b = rowid >> 13;
  int s = (rowid >> 4) & (S - 1);
  __shared__ float row[131];
  int idxn = idx_dn[rowid];
  if (t < 3) row[t] = xyzp[((size_t)b * N + idxn) * 4 + t] - new_xyz[((size_t)b * S + s) * 3 + t];
  row[3 + t] = feats[((size_t)b * N + idxn) * F + t];
  __syncthreads();
  float acc = b0[t];
  for (int i = 0; i < 131; i++) acc = fmaf(row[i], w0[i * F + t], acc);
  act0[(size_t)rowid * F + t] = acc;
}

// ---------------------------------------------------------------- batchnorm stats
__global__ __launch_bounds__(256) void bn_reduce_kernel(const float* __restrict__ x,
                                                        float* __restrict__ sums) {
  __shared__ float ls[256], ls2[256];
  int t = threadIdx.x;
  size_t base = (size_t)blockIdx.x * 65536 + t;
  float s = 0.f, s2 = 0.f;
  for (int i = 0; i < 256; i++) {
    float v = x[base + (size_t)i * 256];
    s += v; s2 = fmaf(v, v, s2);
  }
  ls[t] = s; ls2[t] = s2; __syncthreads();
  if (t < 128) {
    s = ls[t] + ls[t + 128]; s2 = ls2[t] + ls2[t + 128];
    atomicAdd(&sums[t], s); atomicAdd(&sums[128 + t], s2);
  }
}

__global__ void bn_finalize_kernel(const float* __restrict__ sums, const float* __restrict__ g,
    const float* __restrict__ bta, float* __restrict__ scale, float* __restrict__ shift) {
  int t = threadIdx.x;
  float m = sums[t] * (1.f / 32768.f);
  float var = sums[128 + t] * (1.f / 32768.f) - m * m;
  float rstd = rsqrtf(var + EPS);
  float sc = g[t] * rstd;
  scale[t] = sc;
  shift[t] = bta[t] - m * sc;
}

// ---------------------------------------------------------------- grouped MLP layer 1 (128 -> 128)
__global__ __launch_bounds__(128) void td1_kernel(const float* __restrict__ act0,
    const float* __restrict__ scale, const float* __restrict__ shift,
    const float* __restrict__ w1, const float* __restrict__ b1, float* __restrict__ act1) {
  int rowid = blockIdx.x, t = threadIdx.x;
  __shared__ float row[128];
  float xn = fmaxf(fmaf(act0[(size_t)rowid * F + t], scale[t], shift[t]), 0.f);
  row[t] = xn; __syncthreads();
  float acc = b1[t];
  for (int i = 0; i < F; i++) acc = fmaf(row[i], w1[i * F + t], acc);
  act1[(size_t)rowid * F + t] = acc;
}

// ---------------------------------------------------------------- BN+relu+max over K
__global__ __launch_bounds__(128) void maxpool_kernel(const float* __restrict__ act1,
    const float* __restrict__ scale, const float* __restrict__ shift, float* __restrict__ new_feats) {
  int bs = blockIdx.x, t = threadIdx.x;
  float sc = scale[t], sh = shift[t];
  float m = -3e38f;
  for (int k = 0; k < K; k++) {
    float v = fmaxf(fmaf(act1[((size_t)bs * K + k) * F + t], sc, sh), 0.f);
    m = fmaxf(m, v);
  }
  new_feats[(size_t)bs * F + t] = m;
}

// ---------------------------------------------------------------- new_x = new_feats @ w_gkern + b
__global__ __launch_bounds__(128) void rowgemm_kernel(const float* __restrict__ in,
    const float* __restrict__ w, const float* __restrict__ bias, float* __restrict__ out) {
  int r = blockIdx.x, t = threadIdx.x;
  __shared__ float row[128];
  row[t] = in[(size_t)r * F + t]; __syncthreads();
  float acc = bias[t];
  for (int i = 0; i < F; i++) acc = fmaf(row[i], w[i * F + t], acc);
  out[(size_t)r * F + t] = acc;
}

// ---------------------------------------------------------------- kk/vv = new_x @ w_k / w_v
__global__ __launch_bounds__(128) void kv_kernel(const float* __restrict__ new_x,
    const float* __restrict__ wk, const float* __restrict__ wvp,
    float* __restrict__ kk, float* __restrict__ vv) {
  int r = blockIdx.x, t = threadIdx.x;
  __shared__ float row[128];
  row[t] = new_x[(size_t)r * F + t]; __syncthreads();
  float ak = 0.f, av = 0.f;
  for (int i = 0; i < F; i++) {
    float x = row[i];
    ak = fmaf(x, wk[i * F + t], ak);
    av = fmaf(x, wvp[i * F + t], av);
  }
  kk[(size_t)r * F + t] = ak;
  vv[(size_t)r * F + t] = av;
}

// ---------------------------------------------------------------- q = (feats @ w_kern + b) @ w_q
__global__ __launch_bounds__(128) void q_kernel(const float* __restrict__ feats,
    const float* __restrict__ w_kern, const float* __restrict__ b_kern,
    const float* __restrict__ w_q, float* __restrict__ q) {
  int r = blockIdx.x, t = threadIdx.x;
  __shared__ float row[128], row2[128];
  row[t] = feats[(size_t)r * F + t]; __syncthreads();
  float acc = b_kern[t];
  for (int i = 0; i < F; i++) acc = fmaf(row[i], w_kern[i * F + t], acc);
  row2[t] = acc; __syncthreads();
  float aq = 0.f;
  for (int i = 0; i < F; i++) aq = fmaf(row2[i], w_q[i * F + t], aq);
  q[(size_t)r * F + t] = aq;
}

// ---------------------------------------------------------------- fused neighbor attention (MFMA bf16)
// 4 waves/block, 1 point per wave (16 neighbor-rows = one M-tile). Three
// 128x128 GEMM layers + pe2 run on v_mfma_f32_16x16x32_bf16. Weights are
// transposed into LDS (stride 136 bf16 => conflict-free ds_read_b128).
// Softmax + aggregation epilogue in f32.
constexpr int WS = 136;  // Abuf/WT row stride (bf16 elems), 272 B = 17*16B
constexpr int VS = 132;  // WVb row stride

__global__ __launch_bounds__(256) void attn_kernel(const float* __restrict__ xyzp,
    const float* __restrict__ q, const float* __restrict__ kk, const float* __restrict__ vv,
    const float* __restrict__ new_xyzp, const int* __restrict__ idx_up,
    const float* __restrict__ feats,
    const float* __restrict__ pe_w1, const float* __restrict__ pe_b1,
    const float* __restrict__ pe_w2, const float* __restrict__ pe_b2,
    const float* __restrict__ at_w1, const float* __restrict__ at_b1,
    const float* __restrict__ at_w2, const float* __restrict__ at_b2,
    const float* __restrict__ w_agg, const float* __restrict__ b_agg,
    float* __restrict__ out) {
  __shared__ short WT[128 * WS];        // 34.8 KB, shared by all 4 waves, per layer
  __shared__ short Abuf[4][16 * WS];    // 17.4 KB, per-wave A operand (bf16)
  __shared__ short WVb[4][16 * VS];     // 16.9 KB, per-wave wv (bf16)
  __shared__ float qsh[4][128];
  __shared__ float resh[4][128];
  __shared__ float pdsh[4][16][4];
  __shared__ int   nbsh[4][16];

  const int t = threadIdx.x, w = t >> 6, lane = t & 63;
  const int c0 = lane & 15, quad = lane >> 4;
  const int p = blockIdx.x * 4 + w;
  const int b = p >> 13;

  // ---- per-point staging (wave-local)
  qsh[w][lane]      = q[(size_t)p * H + lane];
  qsh[w][lane + 64] = q[(size_t)p * H + lane + 64];
  if (lane < 16) nbsh[w][lane] = idx_up[(size_t)p * K + lane];
  {
    int k = lane >> 2, d = lane & 3;   // 64 lanes cover 16x4
    pdsh[w][k][d] = xyzp[(size_t)p * 4 + d] - new_xyzp[((size_t)b * S + nbsh[w][k]) * 4 + d];
  }
  // ---- pe layer 1 (4 -> 128, relu) -> Abuf bf16
  #pragma unroll
  for (int cc = 0; cc < 2; cc++) {
    int c = cc * 64 + lane;
    float bb = pe_b1[c];
    float w0 = pe_w1[c], w1 = pe_w1[128 + c], w2 = pe_w1[256 + c], w3 = pe_w1[384 + c];
    #pragma unroll
    for (int k = 0; k < 16; k++) {
      float h = bb + pdsh[w][k][0] * w0 + pdsh[w][k][1] * w1 + pdsh[w][k][2] * w2 + pdsh[w][k][3] * w3;
      Abuf[w][k * WS + c] = f2bf(fmaxf(h, 0.f));
    }
  }

  // ---- helpers
  auto stageW = [&](const float* __restrict__ Wg) {
    __syncthreads();                       // all waves done reading previous WT
    #pragma unroll 4
    for (int i = 0; i < 64; i++) {
      int g = t + 256 * i;                 // coalesced global read
      int kx = g >> 7, n = g & 127;
      WT[n * WS + kx] = f2bf(Wg[g]);       // transposed into LDS
    }
    __syncthreads();
  };
  auto gemm = [&](const float* __restrict__ bias, v4f* acc) {
    #pragma unroll
    for (int nt = 0; nt < 8; nt++) {
      float bv = bias[nt * 16 + c0];
      acc[nt] = (v4f){bv, bv, bv, bv};
    }
    #pragma unroll
    for (int ks = 0; ks < 4; ks++) {
      v8s a = *(const v8s*)&Abuf[w][c0 * WS + ks * 32 + quad * 8];
      #pragma unroll
      for (int nt = 0; nt < 8; nt++) {
        v8s bf = *(const v8s*)&WT[(nt * 16 + c0) * WS + ks * 32 + quad * 8];
        acc[nt] = __builtin_amdgcn_mfma_f32_16x16x32_bf16(a, bf, acc[nt], 0, 0, 0);
      }
    }
  };

  // ---- pe layer 2 (GEMM, no relu)
  stageW(pe_w2);
  v4f pe[8];
  gemm(pe_b2, pe);

  // ---- av = q - kk + pe ; wv = vv + pe   (bf16 into Abuf / WVb)
  #pragma unroll
  for (int nt = 0; nt < 8; nt++) {
    #pragma unroll
    for (int r = 0; r < 4; r++) {
      int krow = quad * 4 + r;
      int c = nt * 16 + c0;
      int nb = nbsh[w][krow];
      float pev = pe[nt][r];
      float avv = qsh[w][c] - kk[((size_t)b * S + nb) * H + c] + pev;
      float wvv = vv[((size_t)b * S + nb) * H + c] + pev;
      Abuf[w][krow * WS + c] = f2bf(avv);
      WVb[w][krow * VS + c] = f2bf(wvv);
    }
  }

  // ---- attn MLP layer 1 (GEMM + relu -> Abuf)
  stageW(at_w1);
  v4f h1[8];
  gemm(at_b1, h1);
  #pragma unroll
  for (int nt = 0; nt < 8; nt++)
    #pragma unroll
    for (int r = 0; r < 4; r++)
      Abuf[w][(quad * 4 + r) * WS + nt * 16 + c0] = f2bf(fmaxf(h1[nt][r], 0.f));

  // ---- attn MLP layer 2 (GEMM -> logits)
  stageW(at_w2);
  v4f lg[8];
  gemm(at_b2, lg);

  // ---- per-channel softmax over 16 neighbors + weighted sum of wv
  const float scale = 0.08838834764831845f;  // 1/sqrt(128)
  #pragma unroll
  for (int nt = 0; nt < 8; nt++) {
    float l0 = lg[nt][0] * scale, l1 = lg[nt][1] * scale;
    float l2 = lg[nt][2] * scale, l3 = lg[nt][3] * scale;
    float m = fmaxf(fmaxf(l0, l1), fmaxf(l2, l3));
    m = fmaxf(m, __shfl_xor(m, 16));
    m = fmaxf(m, __shfl_xor(m, 32));
    float e0 = expf(l0 - m), e1 = expf(l1 - m), e2 = expf(l2 - m), e3 = expf(l3 - m);
    float ssum = e0 + e1 + e2 + e3;
    ssum += __shfl_xor(ssum, 16);
    ssum += __shfl_xor(ssum, 32);
    float inv = 1.f / ssum;
    int c = nt * 16 + c0;
    float partial =
        e0 * bf2f(WVb[w][(quad * 4 + 0) * VS + c]) + e1 * bf2f(WVb[w][(quad * 4 + 1) * VS + c]) +
        e2 * bf2f(WVb[w][(quad * 4 + 2) * VS + c]) + e3 * bf2f(WVb[w][(quad * 4 + 3) * VS + c]);
    partial += __shfl_xor(partial, 16);
    partial += __shfl_xor(partial, 32);
    if (quad == 0) resh[w][c] = partial * inv;
  }

  // ---- aggregation epilogue (f32): out = res @ w_agg + b_agg + feats
  #pragma unroll
  for (int cc = 0; cc < 2; cc++) {
    int c = cc * 64 + lane;
    float o = b_agg[c];
    for (int i = 0; i < H; i++) o = fmaf(resh[w][i], w_agg[i * H + c], o);
    out[(size_t)p * F + c] = o + feats[(size_t)p * F + c];
  }
}

// ================================================================ host
extern "C" void kernel_launch(void* const* d_in, const int* in_sizes, int n_in,
                              void* d_out, int out_size, void* d_ws, size_t ws_size,
                              hipStream_t stream) {
  (void)in_sizes; (void)n_in; (void)out_size; (void)ws_size;
  const float* xyzp    = (const float*)d_in[0];
  const float* features= (const float*)d_in[1];
  const float* ln_g    = (const float*)d_in[2];
  const float* ln_b    = (const float*)d_in[3];
  const float* td_w0   = (const float*)d_in[4];
  const float* td_b0   = (const float*)d_in[5];
  const float* bn0_g   = (const float*)d_in[6];
  const float* bn0_b   = (const float*)d_in[7];
  const float* td_w1   = (const float*)d_in[8];
  const float* td_b1   = (const float*)d_in[9];
  const float* bn1_g   = (const float*)d_in[10];
  const float* bn1_b   = (const float*)d_in[11];
  const float* w_kern  = (const float*)d_in[12];
  const float* b_kern  = (const float*)d_in[13];
  const float* w_gkern = (const float*)d_in[14];
  const float* b_gkern = (const float*)d_in[15];
  const float* w_agg   = (const float*)d_in[16];
  const float* b_agg   = (const float*)d_in[17];
  const float* w_q     = (const float*)d_in[18];
  const float* w_k     = (const float*)d_in[19];
  const float* w_v     = (const float*)d_in[20];
  const float* pe_w1   = (const float*)d_in[21];
  const float* pe_b1   = (const float*)d_in[22];
  const float* pe_w2   = (const float*)d_in[23];
  const float* pe_b2   = (const float*)d_in[24];
  const float* at_w1   = (const float*)d_in[25];
  const float* at_b1   = (const float*)d_in[26];
  const float* at_w2   = (const float*)d_in[27];
  const float* at_b2   = (const float*)d_in[28];
  float* out = (float*)d_out;

  float* wsf = (float*)d_ws;
  float* feats     = wsf + 0;           // 4194304
  float* q         = wsf + 4194304;     // 4194304
  float* act0      = wsf + 8388608;     // 4194304
  float* act1      = wsf + 12582912;    // 4194304
  float* new_feats = wsf + 16777216;    // 262144
  float* new_x     = wsf + 17039360;    // 262144
  float* kk        = wsf + 17301504;    // 262144
  float* vv        = wsf + 17563648;    // 262144
  float* new_xyz   = wsf + 17825792;    // 6144
  float* new_xyzp  = wsf + 17831936;    // 8192
  float* sums0     = wsf + 17840128;    // 256
  float* sums1     = wsf + 17840384;    // 256
  float* sc0       = wsf + 17840640;    // 128
  float* sh0       = wsf + 17840768;    // 128
  float* sc1       = wsf + 17840896;    // 128
  float* sh1       = wsf + 17841024;    // 128
  int* idx_dn  = (int*)(wsf + 17841152);
  int* idx_up  = idx_dn + 32768;

  hipMemsetAsync(sums0, 0, 512 * sizeof(float), stream);
  ln_kernel<<<B * N, 128, 0, stream>>>(features, ln_g, ln_b, feats);
  fps_kernel<<<B, 1024, 0, stream>>>(xyzp, new_xyz);
  knn_dn_kernel<<<512, 256, 0, stream>>>(xyzp, new_xyz, idx_dn, new_xyzp);
  knn_up_kernel<<<8192, 256, 0, stream>>>(xyzp, new_xyz, idx_up);
  td0_kernel<<<B * S * K, 128, 0, stream>>>(xyzp, new_xyz, feats, idx_dn, td_w0, td_b0, act0);
  bn_reduce_kernel<<<64, 256, 0, stream>>>(act0, sums0);
  bn_finalize_kernel<<<1, 128, 0, stream>>>(sums0, bn0_g, bn0_b, sc0, sh0);
  td1_kernel<<<B * S * K, 128, 0, stream>>>(act0, sc0, sh0, td_w1, td_b1, act1);
  bn_reduce_kernel<<<64, 256, 0, stream>>>(act1, sums1);
  bn_finalize_kernel<<<1, 128, 0, stream>>>(sums1, bn1_g, bn1_b, sc1, sh1);
  maxpool_kernel<<<B * S, 128, 0, stream>>>(act1, sc1, sh1, new_feats);
  rowgemm_kernel<<<B * S, 128, 0, stream>>>(new_feats, w_gkern, b_gkern, new_x);
  kv_kernel<<<B * S, 128, 0, stream>>>(new_x, w_k, w_v, kk, vv);
  q_kernel<<<B * N, 128, 0, stream>>>(feats, w_kern, b_kern, w_q, q);
  attn_kernel<<<8192, 256, 0, stream>>>(xyzp, q, kk, vv, new_xyzp, idx_up, feats,
      pe_w1, pe_b1, pe_w2, pe_b2, at_w1, at_b1, at_w2, at_b2, w_agg, b_agg, out);
}

// Round 5
// 2218.771 us; speedup vs baseline: 2.4407x; 1.0935x over previous
//
#include <hip/hip_runtime.h>

constexpr int B = 4, N = 8192, S = 512, K = 16, F = 128, H = 128;
constexpr float EPS = 1e-5f;

typedef short v8s __attribute__((ext_vector_type(8)));
typedef float v4f __attribute__((ext_vector_type(4)));

__device__ __forceinline__ short f2bf(float x) {
  union { float f; unsigned u; } v; v.f = x;
  unsigned r = v.u + 0x7fffu + ((v.u >> 16) & 1u);   // RNE
  return (short)(r >> 16);
}
__device__ __forceinline__ float bf2f(short s) {
  union { unsigned u; float f; } v; v.u = ((unsigned)(unsigned short)s) << 16;
  return v.f;
}

// ---------------------------------------------------------------- layernorm
__global__ __launch_bounds__(128) void ln_kernel(const float* __restrict__ features,
    const float* __restrict__ g, const float* __restrict__ bta, float* __restrict__ feats) {
  int r = blockIdx.x, t = threadIdx.x;
  __shared__ float red[128];
  float v = features[(size_t)r * F + t];
  red[t] = v; __syncthreads();
  #pragma unroll
  for (int off = 64; off > 0; off >>= 1) { if (t < off) red[t] += red[t + off]; __syncthreads(); }
  float m = red[0] * (1.f / F);
  __syncthreads();
  float d = v - m;
  red[t] = d * d; __syncthreads();
  #pragma unroll
  for (int off = 64; off > 0; off >>= 1) { if (t < off) red[t] += red[t + off]; __syncthreads(); }
  float var = red[0] * (1.f / F);
  float rstd = rsqrtf(var + EPS);
  feats[(size_t)r * F + t] = d * rstd * g[t] + bta[t];
}

// ---------------------------------------------------------------- FPS
// One barrier per step. Wave-level argmax via 6-step (v,i) shfl butterfly;
// winner coords pulled from winner lane's registers (uniform-index select +
// 3 shfls). Per-wave results in parity-double-buffered LDS slots; all waves
// redundantly reduce the 16 slots (no idle-wave phase, no extra barrier).
__global__ __launch_bounds__(1024) void fps_kernel(const float* __restrict__ xyzp,
    float* __restrict__ new_xyz) {
  int b = blockIdx.x, t = threadIdx.x;
  const float4* xp = (const float4*)(xyzp + (size_t)b * N * 4);
  float px[8], py[8], pz[8], mind[8];
  #pragma unroll
  for (int j = 0; j < 8; j++) {
    float4 p = xp[t + 1024 * j];
    px[j] = p.x; py[j] = p.y; pz[j] = p.z;
    mind[j] = 1e10f;
  }
  __shared__ float4 slotV[2][16];   // (v, x, y, z)
  __shared__ int    slotI[2][16];
  int lane = t & 63, wid = t >> 6;
  float4 p0 = xp[0];
  float lx = p0.x, ly = p0.y, lz = p0.z;
  if (t == 0) {
    new_xyz[(size_t)b * S * 3 + 0] = lx;
    new_xyz[(size_t)b * S * 3 + 1] = ly;
    new_xyz[(size_t)b * S * 3 + 2] = lz;
  }
  for (int s = 1; s < S; ++s) {
    float bv = -1.f; int bi = 0;
    #pragma unroll
    for (int j = 0; j < 8; j++) {
      float dx = __fsub_rn(px[j], lx), dy = __fsub_rn(py[j], ly), dz = __fsub_rn(pz[j], lz);
      float d = __fadd_rn(__fadd_rn(__fmul_rn(dx, dx), __fmul_rn(dy, dy)), __fmul_rn(dz, dz));
      mind[j] = fminf(mind[j], d);
      if (mind[j] > bv) { bv = mind[j]; bi = t + 1024 * j; }  // j asc -> lowest idx on tie
    }
    #pragma unroll
    for (int off = 32; off > 0; off >>= 1) {
      float ov = __shfl_xor(bv, off); int oi = __shfl_xor(bi, off);
      if (ov > bv || (ov == bv && oi < bi)) { bv = ov; bi = oi; }
    }
    // all lanes now hold the wave winner (bv, bi). Extract winner coords:
    int jw = bi >> 10;      // uniform within wave
    int wl = bi & 63;       // winner lane
    float xs = px[0], ys = py[0], zs = pz[0];
    #pragma unroll
    for (int j = 1; j < 8; j++) if (jw == j) { xs = px[j]; ys = py[j]; zs = pz[j]; }
    xs = __shfl(xs, wl); ys = __shfl(ys, wl); zs = __shfl(zs, wl);
    int par = s & 1;
    if (lane == 0) { slotV[par][wid] = make_float4(bv, xs, ys, zs); slotI[par][wid] = bi; }
    __syncthreads();
    float4 sv = slotV[par][lane & 15];
    int    si = slotI[par][lane & 15];
    float v = sv.x; int i2 = si;
    #pragma unroll
    for (int off = 8; off > 0; off >>= 1) {
      float ov = __shfl_xor(v, off); int oi = __shfl_xor(i2, off);
      if (ov > v || (ov == v && oi < i2)) { v = ov; i2 = oi; }
    }
    int wwv = (i2 & 1023) >> 6;   // winning wave == slot index; lane wwv holds it
    lx = __shfl(sv.y, wwv);
    ly = __shfl(sv.z, wwv);
    lz = __shfl(sv.w, wwv);
    if (t == 0) {
      new_xyz[((size_t)b * S + s) * 3 + 0] = lx;
      new_xyz[((size_t)b * S + s) * 3 + 1] = ly;
      new_xyz[((size_t)b * S + s) * 3 + 2] = lz;
    }
  }
}

// ---------------------------------------------------------------- kNN: 512 queries vs 8192 refs
__global__ __launch_bounds__(256) void knn_dn_kernel(const float* __restrict__ xyzp,
    const float* __restrict__ new_xyz, int* __restrict__ idx_dn, float* __restrict__ new_xyzp) {
  int wave = threadIdx.x >> 6, lane = threadIdx.x & 63;
  int qid = blockIdx.x * 4 + wave;
  int b = qid >> 9, s = qid & (S - 1);
  const float4* xp = (const float4*)(xyzp + (size_t)b * N * 4);
  float qx = new_xyz[((size_t)b * S + s) * 3 + 0];
  float qy = new_xyz[((size_t)b * S + s) * 3 + 1];
  float qz = new_xyz[((size_t)b * S + s) * 3 + 2];
  float qq = __fadd_rn(__fadd_rn(__fmul_rn(qx, qx), __fmul_rn(qy, qy)), __fmul_rn(qz, qz));

  float lastD = -1.f; int lastI = -1;
  float curD; int curI;
  auto scan = [&]() {
    curD = 3e38f; curI = 0x7fffffff;
    for (int j = 0; j < 128; j++) {
      int i = lane + 64 * j;
      float4 p = xp[i];
      float rr  = __fadd_rn(__fadd_rn(__fmul_rn(p.x, p.x), __fmul_rn(p.y, p.y)), __fmul_rn(p.z, p.z));
      float dot = __fadd_rn(__fadd_rn(__fmul_rn(qx, p.x), __fmul_rn(qy, p.y)), __fmul_rn(qz, p.z));
      float d2 = __fsub_rn(__fadd_rn(qq, rr), __fmul_rn(2.0f, dot));
      bool gate   = (d2 > lastD) || (d2 == lastD && i > lastI);
      bool better = (d2 < curD) || (d2 == curD && i < curI);
      if (gate && better) { curD = d2; curI = i; }
    }
  };
  scan();
  int outI = 0;
  float4 nn0;
  #pragma unroll 1
  for (int r = 0; r < K; r++) {
    float mD = curD; int mI = curI; int mL = lane;
    #pragma unroll
    for (int off = 32; off > 0; off >>= 1) {
      float od = __shfl_xor(mD, off); int oi = __shfl_xor(mI, off); int ol = __shfl_xor(mL, off);
      if (od < mD || (od == mD && oi < mI)) { mD = od; mI = oi; mL = ol; }
    }
    if (lane == r) outI = mI;
    if (r == 0 && lane == 0) nn0 = xp[mI];
    if (lane == mL) { lastD = mD; lastI = mI; scan(); }
  }
  size_t base = ((size_t)b * S + s) * K;
  if (lane < K) idx_dn[base + lane] = outI;
  if (lane == 0) *(float4*)&new_xyzp[((size_t)b * S + s) * 4] = nn0;
}

// ---------------------------------------------------------------- kNN: 8192 queries vs 512 refs
__global__ __launch_bounds__(256) void knn_up_kernel(const float* __restrict__ xyzp,
    const float* __restrict__ new_xyz, int* __restrict__ idx_up) {
  int wave = threadIdx.x >> 6, lane = threadIdx.x & 63;
  int qid = blockIdx.x * 4 + wave;
  int b = qid >> 13, n = qid & (N - 1);
  const float4* xp = (const float4*)(xyzp + (size_t)b * N * 4);
  float4 qp = xp[n];
  float qx = qp.x, qy = qp.y, qz = qp.z;
  float qq = __fadd_rn(__fadd_rn(__fmul_rn(qx, qx), __fmul_rn(qy, qy)), __fmul_rn(qz, qz));
  float rx[8], ry[8], rz[8];
  #pragma unroll
  for (int j = 0; j < 8; j++) {
    int i = lane + 64 * j;
    rx[j] = new_xyz[((size_t)b * S + i) * 3 + 0];
    ry[j] = new_xyz[((size_t)b * S + i) * 3 + 1];
    rz[j] = new_xyz[((size_t)b * S + i) * 3 + 2];
  }
  float lastD = -1.f; int lastI = -1;
  float curD; int curI;
  auto scan = [&]() {
    curD = 3e38f; curI = 0x7fffffff;
    #pragma unroll
    for (int j = 0; j < 8; j++) {
      int i = lane + 64 * j;
      float rr  = __fadd_rn(__fadd_rn(__fmul_rn(rx[j], rx[j]), __fmul_rn(ry[j], ry[j])), __fmul_rn(rz[j], rz[j]));
      float dot = __fadd_rn(__fadd_rn(__fmul_rn(qx, rx[j]), __fmul_rn(qy, ry[j])), __fmul_rn(qz, rz[j]));
      float d2 = __fsub_rn(__fadd_rn(qq, rr), __fmul_rn(2.0f, dot));
      bool gate   = (d2 > lastD) || (d2 == lastD && i > lastI);
      bool better = (d2 < curD) || (d2 == curD && i < curI);
      if (gate && better) { curD = d2; curI = i; }
    }
  };
  scan();
  int outI = 0;
  #pragma unroll 1
  for (int r = 0; r < K; r++) {
    float mD = curD; int mI = curI; int mL = lane;
    #pragma unroll
    for (int off = 32; off > 0; off >>= 1) {
      float od = __shfl_xor(mD, off); int oi = __shfl_xor(mI, off); int ol = __shfl_xor(mL, off);
      if (od < mD || (od == mD && oi < mI)) { mD = od; mI = oi; mL = ol; }
    }
    if (lane == r) outI = mI;
    if (lane == mL) { lastD = mD; lastI = mI; scan(); }
  }
  size_t base = ((size_t)b * N + n) * K;
  if (lane < K) idx_up[base + lane] = outI;
}

// ---------------------------------------------------------------- td layer 0 (131 -> 128, MFMA)
// 64 rows/block (16/wave); weight transposed+staged once per block.
constexpr int KS0 = 168;  // 160-pad K, +8 -> 336 B stride (odd multiple of 16 B)
__global__ __launch_bounds__(256) void td0_mfma(const float* __restrict__ xyzp,
    const float* __restrict__ new_xyz, const float* __restrict__ feats,
    const int* __restrict__ idx_dn, const float* __restrict__ w0, const float* __restrict__ b0,
    float* __restrict__ act0) {
  __shared__ short WT[128 * KS0];
  __shared__ short Abuf[4][16 * KS0];
  __shared__ int nbs[4][16];
  const int t = threadIdx.x, w = t >> 6, lane = t & 63;
  const int c0 = lane & 15, quad = lane >> 4;
  const int row0 = blockIdx.x * 64 + w * 16;
  const int bI = row0 >> 13;
  if (lane < 16) {
    int nb = idx_dn[row0 + lane];
    nbs[w][lane] = nb;
    int s = ((row0 + lane) >> 4) & (S - 1);
    #pragma unroll
    for (int d = 0; d < 3; d++)
      Abuf[w][lane * KS0 + d] =
          f2bf(xyzp[((size_t)bI * N + nb) * 4 + d] - new_xyz[((size_t)bI * S + s) * 3 + d]);
    for (int k2 = 131; k2 < 160; k2++) Abuf[w][lane * KS0 + k2] = 0;
  }
  #pragma unroll 4
  for (int i = 0; i < 32; i++) {
    int idx = lane + 64 * i;
    int r = idx >> 7, c = idx & 127;
    int nb = nbs[w][r];
    Abuf[w][r * KS0 + 3 + c] = f2bf(feats[((size_t)bI * N + nb) * F + c]);
  }
  #pragma unroll 4
  for (int i = 0; i < 66; i++) {
    int g = t + 256 * i;
    if (g < 131 * 128) {
      int kx = g >> 7, n = g & 127;
      WT[n * KS0 + kx] = f2bf(w0[g]);
    }
  }
  #pragma unroll
  for (int i = 0; i < 15; i++) {
    int g2 = t + 256 * i;
    int kz = 131 + (g2 >> 7), n = g2 & 127;
    if (kz < 160) WT[n * KS0 + kz] = 0;
  }
  __syncthreads();
  v4f acc[8];
  #pragma unroll
  for (int nt = 0; nt < 8; nt++) { float bvv = b0[nt * 16 + c0]; acc[nt] = (v4f){bvv, bvv, bvv, bvv}; }
  #pragma unroll
  for (int ks = 0; ks < 5; ks++) {
    v8s a = *(const v8s*)&Abuf[w][c0 * KS0 + ks * 32 + quad * 8];
    #pragma unroll
    for (int nt = 0; nt < 8; nt++) {
      v8s bf = *(const v8s*)&WT[(nt * 16 + c0) * KS0 + ks * 32 + quad * 8];
      acc[nt] = __builtin_amdgcn_mfma_f32_16x16x32_bf16(a, bf, acc[nt], 0, 0, 0);
    }
  }
  #pragma unroll
  for (int nt = 0; nt < 8; nt++)
    #pragma unroll
    for (int r = 0; r < 4; r++)
      act0[(size_t)(row0 + quad * 4 + r) * F + nt * 16 + c0] = acc[nt][r];
}

// ---------------------------------------------------------------- batchnorm stats
__global__ __launch_bounds__(256) void bn_reduce_kernel(const float* __restrict__ x,
                                                        float* __restrict__ sums) {
  __shared__ float ls[256], ls2[256];
  int t = threadIdx.x;
  size_t base = (size_t)blockIdx.x * 65536 + t;
  float s = 0.f, s2 = 0.f;
  for (int i = 0; i < 256; i++) {
    float v = x[base + (size_t)i * 256];
    s += v; s2 = fmaf(v, v, s2);
  }
  ls[t] = s; ls2[t] = s2; __syncthreads();
  if (t < 128) {
    s = ls[t] + ls[t + 128]; s2 = ls2[t] + ls2[t + 128];
    atomicAdd(&sums[t], s); atomicAdd(&sums[128 + t], s2);
  }
}

__global__ void bn_finalize_kernel(const float* __restrict__ sums, const float* __restrict__ g,
    const float* __restrict__ bta, float* __restrict__ scale, float* __restrict__ shift) {
  int t = threadIdx.x;
  float m = sums[t] * (1.f / 32768.f);
  float var = sums[128 + t] * (1.f / 32768.f) - m * m;
  float rstd = rsqrtf(var + EPS);
  float sc = g[t] * rstd;
  scale[t] = sc;
  shift[t] = bta[t] - m * sc;
}

// ---------------------------------------------------------------- td layer 1 (128 -> 128, MFMA)
constexpr int KS1 = 136;
__global__ __launch_bounds__(256) void td1_mfma(const float* __restrict__ act0,
    const float* __restrict__ scale, const float* __restrict__ shift,
    const float* __restrict__ w1, const float* __restrict__ b1, float* __restrict__ act1) {
  __shared__ short WT[128 * KS1];
  __shared__ short Abuf[4][16 * KS1];
  __shared__ float scs[128], shs[128];
  const int t = threadIdx.x, w = t >> 6, lane = t & 63;
  const int c0 = lane & 15, quad = lane >> 4;
  const int row0 = blockIdx.x * 64 + w * 16;
  if (t < 128) { scs[t] = scale[t]; shs[t] = shift[t]; }
  #pragma unroll 4
  for (int i = 0; i < 64; i++) {
    int g = t + 256 * i;
    int kx = g >> 7, n = g & 127;
    WT[n * KS1 + kx] = f2bf(w1[g]);
  }
  __syncthreads();
  #pragma unroll 4
  for (int i = 0; i < 32; i++) {
    int idx = lane + 64 * i;
    int r = idx >> 7, c = idx & 127;
    float vv = fmaxf(fmaf(act0[(size_t)(row0 + r) * F + c], scs[c], shs[c]), 0.f);
    Abuf[w][r * KS1 + c] = f2bf(vv);
  }
  v4f acc[8];
  #pragma unroll
  for (int nt = 0; nt < 8; nt++) { float bvv = b1[nt * 16 + c0]; acc[nt] = (v4f){bvv, bvv, bvv, bvv}; }
  #pragma unroll
  for (int ks = 0; ks < 4; ks++) {
    v8s a = *(const v8s*)&Abuf[w][c0 * KS1 + ks * 32 + quad * 8];
    #pragma unroll
    for (int nt = 0; nt < 8; nt++) {
      v8s bf = *(const v8s*)&WT[(nt * 16 + c0) * KS1 + ks * 32 + quad * 8];
      acc[nt] = __builtin_amdgcn_mfma_f32_16x16x32_bf16(a, bf, acc[nt], 0, 0, 0);
    }
  }
  #pragma unroll
  for (int nt = 0; nt < 8; nt++)
    #pragma unroll
    for (int r = 0; r < 4; r++)
      act1[(size_t)(row0 + quad * 4 + r) * F + nt * 16 + c0] = acc[nt][r];
}

// ---------------------------------------------------------------- BN+relu+max over K
__global__ __launch_bounds__(128) void maxpool_kernel(const float* __restrict__ act1,
    const float* __restrict__ scale, const float* __restrict__ shift, float* __restrict__ new_feats) {
  int bs = blockIdx.x, t = threadIdx.x;
  float sc = scale[t], sh = shift[t];
  float m = -3e38f;
  for (int k = 0; k < K; k++) {
    float v = fmaxf(fmaf(act1[((size_t)bs * K + k) * F + t], sc, sh), 0.f);
    m = fmaxf(m, v);
  }
  new_feats[(size_t)bs * F + t] = m;
}

// ---------------------------------------------------------------- new_x = new_feats @ w_gkern + b
__global__ __launch_bounds__(128) void rowgemm_kernel(const float* __restrict__ in,
    const float* __restrict__ w, const float* __restrict__ bias, float* __restrict__ out) {
  int r = blockIdx.x, t = threadIdx.x;
  __shared__ float row[128];
  row[t] = in[(size_t)r * F + t]; __syncthreads();
  float acc = bias[t];
  for (int i = 0; i < F; i++) acc = fmaf(row[i], w[i * F + t], acc);
  out[(size_t)r * F + t] = acc;
}

// ---------------------------------------------------------------- kk/vv = new_x @ w_k / w_v
__global__ __launch_bounds__(128) void kv_kernel(const float* __restrict__ new_x,
    const float* __restrict__ wk, const float* __restrict__ wvp,
    float* __restrict__ kk, float* __restrict__ vv) {
  int r = blockIdx.x, t = threadIdx.x;
  __shared__ float row[128];
  row[t] = new_x[(size_t)r * F + t]; __syncthreads();
  float ak = 0.f, av = 0.f;
  for (int i = 0; i < F; i++) {
    float x = row[i];
    ak = fmaf(x, wk[i * F + t], ak);
    av = fmaf(x, wvp[i * F + t], av);
  }
  kk[(size_t)r * F + t] = ak;
  vv[(size_t)r * F + t] = av;
}

// ---------------------------------------------------------------- q = (feats @ w_kern + b) @ w_q  (MFMA)
__global__ __launch_bounds__(256) void q_mfma(const float* __restrict__ feats,
    const float* __restrict__ w_kern, const float* __restrict__ b_kern,
    const float* __restrict__ w_q, float* __restrict__ q) {
  __shared__ short WT[128 * KS1];
  __shared__ short Abuf[4][16 * KS1];
  const int t = threadIdx.x, w = t >> 6, lane = t & 63;
  const int c0 = lane & 15, quad = lane >> 4;
  const int row0 = blockIdx.x * 64 + w * 16;
  #pragma unroll 4
  for (int i = 0; i < 32; i++) {
    int idx = lane + 64 * i;
    int r = idx >> 7, c = idx & 127;
    Abuf[w][r * KS1 + c] = f2bf(feats[(size_t)(row0 + r) * F + c]);
  }
  #pragma unroll 4
  for (int i = 0; i < 64; i++) {
    int g = t + 256 * i;
    int kx = g >> 7, n = g & 127;
    WT[n * KS1 + kx] = f2bf(w_kern[g]);
  }
  __syncthreads();
  v4f acc[8];
  #pragma unroll
  for (int nt = 0; nt < 8; nt++) { float bvv = b_kern[nt * 16 + c0]; acc[nt] = (v4f){bvv, bvv, bvv, bvv}; }
  #pragma unroll
  for (int ks = 0; ks < 4; ks++) {
    v8s a = *(const v8s*)&Abuf[w][c0 * KS1 + ks * 32 + quad * 8];
    #pragma unroll
    for (int nt = 0; nt < 8; nt++) {
      v8s bf = *(const v8s*)&WT[(nt * 16 + c0) * KS1 + ks * 32 + quad * 8];
      acc[nt] = __builtin_amdgcn_mfma_f32_16x16x32_bf16(a, bf, acc[nt], 0, 0, 0);
    }
  }
  __syncthreads();   // all waves done reading WT (layer 1)
  #pragma unroll 4
  for (int i = 0; i < 64; i++) {
    int g = t + 256 * i;
    int kx = g >> 7, n = g & 127;
    WT[n * KS1 + kx] = f2bf(w_q[g]);
  }
  #pragma unroll
  for (int nt = 0; nt < 8; nt++)
    #pragma unroll
    for (int r = 0; r < 4; r++)
      Abuf[w][(quad * 4 + r) * KS1 + nt * 16 + c0] = f2bf(acc[nt][r]);
  __syncthreads();
  v4f acc2[8];
  #pragma unroll
  for (int nt = 0; nt < 8; nt++) acc2[nt] = (v4f){0.f, 0.f, 0.f, 0.f};
  #pragma unroll
  for (int ks = 0; ks < 4; ks++) {
    v8s a = *(const v8s*)&Abuf[w][c0 * KS1 + ks * 32 + quad * 8];
    #pragma unroll
    for (int nt = 0; nt < 8; nt++) {
      v8s bf = *(const v8s*)&WT[(nt * 16 + c0) * KS1 + ks * 32 + quad * 8];
      acc2[nt] = __builtin_amdgcn_mfma_f32_16x16x32_bf16(a, bf, acc2[nt], 0, 0, 0);
    }
  }
  #pragma unroll
  for (int nt = 0; nt < 8; nt++)
    #pragma unroll
    for (int r = 0; r < 4; r++)
      q[(size_t)(row0 + quad * 4 + r) * F + nt * 16 + c0] = acc2[nt][r];
}

// ---------------------------------------------------------------- fused neighbor attention (MFMA bf16)
constexpr int WS = 136;
constexpr int VS = 132;

__global__ __launch_bounds__(256) void attn_kernel(const float* __restrict__ xyzp,
    const float* __restrict__ q, const float* __restrict__ kk, const float* __restrict__ vv,
    const float* __restrict__ new_xyzp, const int* __restrict__ idx_up,
    const float* __restrict__ feats,
    const float* __restrict__ pe_w1, const float* __restrict__ pe_b1,
    const float* __restrict__ pe_w2, const float* __restrict__ pe_b2,
    const float* __restrict__ at_w1, const float* __restrict__ at_b1,
    const float* __restrict__ at_w2, const float* __restrict__ at_b2,
    const float* __restrict__ w_agg, const float* __restrict__ b_agg,
    float* __restrict__ out) {
  __shared__ short WT[128 * WS];
  __shared__ short Abuf[4][16 * WS];
  __shared__ short WVb[4][16 * VS];
  __shared__ float qsh[4][128];
  __shared__ float resh[4][128];
  __shared__ float pdsh[4][16][4];
  __shared__ int   nbsh[4][16];

  const int t = threadIdx.x, w = t >> 6, lane = t & 63;
  const int c0 = lane & 15, quad = lane >> 4;
  const int p = blockIdx.x * 4 + w;
  const int b = p >> 13;

  qsh[w][lane]      = q[(size_t)p * H + lane];
  qsh[w][lane + 64] = q[(size_t)p * H + lane + 64];
  if (lane < 16) nbsh[w][lane] = idx_up[(size_t)p * K + lane];
  {
    int k = lane >> 2, d = lane & 3;
    pdsh[w][k][d] = xyzp[(size_t)p * 4 + d] - new_xyzp[((size_t)b * S + nbsh[w][k]) * 4 + d];
  }
  #pragma unroll
  for (int cc = 0; cc < 2; cc++) {
    int c = cc * 64 + lane;
    float bb = pe_b1[c];
    float w0 = pe_w1[c], w1 = pe_w1[128 + c], w2 = pe_w1[256 + c], w3 = pe_w1[384 + c];
    #pragma unroll
    for (int k = 0; k < 16; k++) {
      float h = bb + pdsh[w][k][0] * w0 + pdsh[w][k][1] * w1 + pdsh[w][k][2] * w2 + pdsh[w][k][3] * w3;
      Abuf[w][k * WS + c] = f2bf(fmaxf(h, 0.f));
    }
  }

  auto stageW = [&](const float* __restrict__ Wg) {
    __syncthreads();
    #pragma unroll 4
    for (int i = 0; i < 64; i++) {
      int g = t + 256 * i;
      int kx = g >> 7, n = g & 127;
      WT[n * WS + kx] = f2bf(Wg[g]);
    }
    __syncthreads();
  };
  auto gemm = [&](const float* __restrict__ bias, v4f* acc) {
    #pragma unroll
    for (int nt = 0; nt < 8; nt++) {
      float bv = bias[nt * 16 + c0];
      acc[nt] = (v4f){bv, bv, bv, bv};
    }
    #pragma unroll
    for (int ks = 0; ks < 4; ks++) {
      v8s a = *(const v8s*)&Abuf[w][c0 * WS + ks * 32 + quad * 8];
      #pragma unroll
      for (int nt = 0; nt < 8; nt++) {
        v8s bf = *(const v8s*)&WT[(nt * 16 + c0) * WS + ks * 32 + quad * 8];
        acc[nt] = __builtin_amdgcn_mfma_f32_16x16x32_bf16(a, bf, acc[nt], 0, 0, 0);
      }
    }
  };

  stageW(pe_w2);
  v4f pe[8];
  gemm(pe_b2, pe);

  #pragma unroll
  for (int nt = 0; nt < 8; nt++) {
    #pragma unroll
    for (int r = 0; r < 4; r++) {
      int krow = quad * 4 + r;
      int c = nt * 16 + c0;
      int nb = nbsh[w][krow];
      float pev = pe[nt][r];
      float avv = qsh[w][c] - kk[((size_t)b * S + nb) * H + c] + pev;
      float wvv = vv[((size_t)b * S + nb) * H + c] + pev;
      Abuf[w][krow * WS + c] = f2bf(avv);
      WVb[w][krow * VS + c] = f2bf(wvv);
    }
  }

  stageW(at_w1);
  v4f h1[8];
  gemm(at_b1, h1);
  #pragma unroll
  for (int nt = 0; nt < 8; nt++)
    #pragma unroll
    for (int r = 0; r < 4; r++)
      Abuf[w][(quad * 4 + r) * WS + nt * 16 + c0] = f2bf(fmaxf(h1[nt][r], 0.f));

  stageW(at_w2);
  v4f lg[8];
  gemm(at_b2, lg);

  const float scale = 0.08838834764831845f;
  #pragma unroll
  for (int nt = 0; nt < 8; nt++) {
    float l0 = lg[nt][0] * scale, l1 = lg[nt][1] * scale;
    float l2 = lg[nt][2] * scale, l3 = lg[nt][3] * scale;
    float m = fmaxf(fmaxf(l0, l1), fmaxf(l2, l3));
    m = fmaxf(m, __shfl_xor(m, 16));
    m = fmaxf(m, __shfl_xor(m, 32));
    float e0 = expf(l0 - m), e1 = expf(l1 - m), e2 = expf(l2 - m), e3 = expf(l3 - m);
    float ssum = e0 + e1 + e2 + e3;
    ssum += __shfl_xor(ssum, 16);
    ssum += __shfl_xor(ssum, 32);
    float inv = 1.f / ssum;
    int c = nt * 16 + c0;
    float partial =
        e0 * bf2f(WVb[w][(quad * 4 + 0) * VS + c]) + e1 * bf2f(WVb[w][(quad * 4 + 1) * VS + c]) +
        e2 * bf2f(WVb[w][(quad * 4 + 2) * VS + c]) + e3 * bf2f(WVb[w][(quad * 4 + 3) * VS + c]);
    partial += __shfl_xor(partial, 16);
    partial += __shfl_xor(partial, 32);
    if (quad == 0) resh[w][c] = partial * inv;
  }

  #pragma unroll
  for (int cc = 0; cc < 2; cc++) {
    int c = cc * 64 + lane;
    float o = b_agg[c];
    for (int i = 0; i < H; i++) o = fmaf(resh[w][i], w_agg[i * H + c], o);
    out[(size_t)p * F + c] = o + feats[(size_t)p * F + c];
  }
}

// ================================================================ host
extern "C" void kernel_launch(void* const* d_in, const int* in_sizes, int n_in,
                              void* d_out, int out_size, void* d_ws, size_t ws_size,
                              hipStream_t stream) {
  (void)in_sizes; (void)n_in; (void)out_size; (void)ws_size;
  const float* xyzp    = (const float*)d_in[0];
  const float* features= (const float*)d_in[1];
  const float* ln_g    = (const float*)d_in[2];
  const float* ln_b    = (const float*)d_in[3];
  const float* td_w0   = (const float*)d_in[4];
  const float* td_b0   = (const float*)d_in[5];
  const float* bn0_g   = (const float*)d_in[6];
  const float* bn0_b   = (const float*)d_in[7];
  const float* td_w1   = (const float*)d_in[8];
  const float* td_b1   = (const float*)d_in[9];
  const float* bn1_g   = (const float*)d_in[10];
  const float* bn1_b   = (const float*)d_in[11];
  const float* w_kern  = (const float*)d_in[12];
  const float* b_kern  = (const float*)d_in[13];
  const float* w_gkern = (const float*)d_in[14];
  const float* b_gkern = (const float*)d_in[15];
  const float* w_agg   = (const float*)d_in[16];
  const float* b_agg   = (const float*)d_in[17];
  const float* w_q     = (const float*)d_in[18];
  const float* w_k     = (const float*)d_in[19];
  const float* w_v     = (const float*)d_in[20];
  const float* pe_w1   = (const float*)d_in[21];
  const float* pe_b1   = (const float*)d_in[22];
  const float* pe_w2   = (const float*)d_in[23];
  const float* pe_b2   = (const float*)d_in[24];
  const float* at_w1   = (const float*)d_in[25];
  const float* at_b1   = (const float*)d_in[26];
  const float* at_w2   = (const float*)d_in[27];
  const float* at_b2   = (const float*)d_in[28];
  float* out = (float*)d_out;

  float* wsf = (float*)d_ws;
  float* feats     = wsf + 0;           // 4194304
  float* q         = wsf + 4194304;     // 4194304
  float* act0      = wsf + 8388608;     // 4194304
  float* act1      = wsf + 12582912;    // 4194304
  float* new_feats = wsf + 16777216;    // 262144
  float* new_x     = wsf + 17039360;    // 262144
  float* kk        = wsf + 17301504;    // 262144
  float* vv        = wsf + 17563648;    // 262144
  float* new_xyz   = wsf + 17825792;    // 6144
  float* new_xyzp  = wsf + 17831936;    // 8192
  float* sums0     = wsf + 17840128;    // 256
  float* sums1     = wsf + 17840384;    // 256
  float* sc0       = wsf + 17840640;    // 128
  float* sh0       = wsf + 17840768;    // 128
  float* sc1       = wsf + 17840896;    // 128
  float* sh1       = wsf + 17841024;    // 128
  int* idx_dn  = (int*)(wsf + 17841152);
  int* idx_up  = idx_dn + 32768;

  hipMemsetAsync(sums0, 0, 512 * sizeof(float), stream);
  ln_kernel<<<B * N, 128, 0, stream>>>(features, ln_g, ln_b, feats);
  fps_kernel<<<B, 1024, 0, stream>>>(xyzp, new_xyz);
  knn_dn_kernel<<<512, 256, 0, stream>>>(xyzp, new_xyz, idx_dn, new_xyzp);
  knn_up_kernel<<<8192, 256, 0, stream>>>(xyzp, new_xyz, idx_up);
  td0_mfma<<<512, 256, 0, stream>>>(xyzp, new_xyz, feats, idx_dn, td_w0, td_b0, act0);
  bn_reduce_kernel<<<64, 256, 0, stream>>>(act0, sums0);
  bn_finalize_kernel<<<1, 128, 0, stream>>>(sums0, bn0_g, bn0_b, sc0, sh0);
  td1_mfma<<<512, 256, 0, stream>>>(act0, sc0, sh0, td_w1, td_b1, act1);
  bn_reduce_kernel<<<64, 256, 0, stream>>>(act1, sums1);
  bn_finalize_kernel<<<1, 128, 0, stream>>>(sums1, bn1_g, bn1_b, sc1, sh1);
  maxpool_kernel<<<B * S, 128, 0, stream>>>(act1, sc1, sh1, new_feats);
  rowgemm_kernel<<<B * S, 128, 0, stream>>>(new_feats, w_gkern, b_gkern, new_x);
  kv_kernel<<<B * S, 128, 0, stream>>>(new_x, w_k, w_v, kk, vv);
  q_mfma<<<512, 256, 0, stream>>>(feats, w_kern, b_kern, w_q, q);
  attn_kernel<<<8192, 256, 0, stream>>>(xyzp, q, kk, vv, new_xyzp, idx_up, feats,
      pe_w1, pe_b1, pe_w2, pe_b2, at_w1, at_b1, at_w2, at_b2, w_agg, b_agg, out);
}

// Round 6
// 1836.129 us; speedup vs baseline: 2.9493x; 1.2084x over previous
//
#include <hip/hip_runtime.h>

constexpr int B = 4, N = 8192, S = 512, K = 16, F = 128, H = 128;
constexpr float EPS = 1e-5f;

typedef short v8s __attribute__((ext_vector_type(8)));
typedef float v4f __attribute__((ext_vector_type(4)));

__device__ __forceinline__ short f2bf(float x) {
  union { float f; unsigned u; } v; v.f = x;
  unsigned r = v.u + 0x7fffu + ((v.u >> 16) & 1u);   // RNE
  return (short)(r >> 16);
}
__device__ __forceinline__ float bf2f(short s) {
  union { unsigned u; float f; } v; v.u = ((unsigned)(unsigned short)s) << 16;
  return v.f;
}

template <int CTRL>
__device__ __forceinline__ float dpp_mov_f(float v) {
  return __int_as_float(__builtin_amdgcn_update_dpp(
      __float_as_int(v), __float_as_int(v), CTRL, 0xF, 0xF, false));
}
template <int CTRL>
__device__ __forceinline__ int dpp_mov_i(int v) {
  return __builtin_amdgcn_update_dpp(v, v, CTRL, 0xF, 0xF, false);
}

// ---------------------------------------------------------------- layernorm
__global__ __launch_bounds__(128) void ln_kernel(const float* __restrict__ features,
    const float* __restrict__ g, const float* __restrict__ bta, float* __restrict__ feats) {
  int r = blockIdx.x, t = threadIdx.x;
  __shared__ float red[128];
  float v = features[(size_t)r * F + t];
  red[t] = v; __syncthreads();
  #pragma unroll
  for (int off = 64; off > 0; off >>= 1) { if (t < off) red[t] += red[t + off]; __syncthreads(); }
  float m = red[0] * (1.f / F);
  __syncthreads();
  float d = v - m;
  red[t] = d * d; __syncthreads();
  #pragma unroll
  for (int off = 64; off > 0; off >>= 1) { if (t < off) red[t] += red[t + off]; __syncthreads(); }
  float var = red[0] * (1.f / F);
  float rstd = rsqrtf(var + EPS);
  feats[(size_t)r * F + t] = d * rstd * g[t] + bta[t];
}

// ---------------------------------------------------------------- FPS
// 256 threads (4 waves), 32 pts/thread in registers. Wave argmax via DPP
// (VALU pipe, zero DS traffic); cross-wave via 4 LDS slots; winner coords
// read from a full LDS mirror of the points (broadcast reads). Total DS ops
// in the serial chain: ~8/step (was ~416 with shfl butterflies @1024 thr).
__global__ __launch_bounds__(256, 1) void fps_kernel(const float* __restrict__ xyzp,
    float* __restrict__ new_xyz) {
  __shared__ float xl[N], yl[N], zl[N];     // 96 KB point mirror
  __shared__ float2 slot[2][4];
  int b = blockIdx.x, t = threadIdx.x;
  int lane = t & 63, wid = t >> 6;
  const float4* xp = (const float4*)(xyzp + (size_t)b * N * 4);
  float px[32], py[32], pz[32], mind[32];
  #pragma unroll
  for (int j = 0; j < 32; j++) {
    int idx = t + 256 * j;
    float4 p = xp[idx];
    px[j] = p.x; py[j] = p.y; pz[j] = p.z; mind[j] = 1e10f;
    xl[idx] = p.x; yl[idx] = p.y; zl[idx] = p.z;
  }
  __syncthreads();
  float cx = xl[0], cy = yl[0], cz = zl[0];
  if (t == 0) {
    new_xyz[(size_t)b * S * 3 + 0] = cx;
    new_xyz[(size_t)b * S * 3 + 1] = cy;
    new_xyz[(size_t)b * S * 3 + 2] = cz;
  }
  for (int s = 1; s < S; ++s) {
    float bv = -1.f; int bi = 0;
    #pragma unroll
    for (int j = 0; j < 32; j++) {
      float dx = __fsub_rn(px[j], cx), dy = __fsub_rn(py[j], cy), dz = __fsub_rn(pz[j], cz);
      float d = __fadd_rn(__fadd_rn(__fmul_rn(dx, dx), __fmul_rn(dy, dy)), __fmul_rn(dz, dz));
      mind[j] = fminf(mind[j], d);
      if (mind[j] > bv) { bv = mind[j]; bi = t + 256 * j; }   // j asc -> lowest idx on tie
    }
    // wave argmax on (bv, bi): DPP row_shr 1/2/4/8 + row_bcast15/31 -> lane 63
    #define FPS_STEP(CTRL) { \
      float ov = dpp_mov_f<CTRL>(bv); int oi = dpp_mov_i<CTRL>(bi); \
      if (ov > bv || (ov == bv && oi < bi)) { bv = ov; bi = oi; } }
    FPS_STEP(0x111) FPS_STEP(0x112) FPS_STEP(0x114) FPS_STEP(0x118)
    FPS_STEP(0x142) FPS_STEP(0x143)
    #undef FPS_STEP
    int par = s & 1;
    if (lane == 63) slot[par][wid] = make_float2(bv, __int_as_float(bi));
    __syncthreads();
    // all threads combine the 4 wave winners (uniform result)
    float2 s0 = slot[par][0], s1 = slot[par][1], s2 = slot[par][2], s3 = slot[par][3];
    float wv = s0.x; int wi = __float_as_int(s0.y);
    { float v2 = s1.x; int i2 = __float_as_int(s1.y);
      if (v2 > wv || (v2 == wv && i2 < wi)) { wv = v2; wi = i2; } }
    { float v2 = s2.x; int i2 = __float_as_int(s2.y);
      if (v2 > wv || (v2 == wv && i2 < wi)) { wv = v2; wi = i2; } }
    { float v2 = s3.x; int i2 = __float_as_int(s3.y);
      if (v2 > wv || (v2 == wv && i2 < wi)) { wv = v2; wi = i2; } }
    cx = xl[wi]; cy = yl[wi]; cz = zl[wi];
    if (t == 0) {
      new_xyz[((size_t)b * S + s) * 3 + 0] = cx;
      new_xyz[((size_t)b * S + s) * 3 + 1] = cy;
      new_xyz[((size_t)b * S + s) * 3 + 2] = cz;
    }
  }
}

// ---------------------------------------------------------------- kNN: 512 queries vs 8192 refs
__global__ __launch_bounds__(256) void knn_dn_kernel(const float* __restrict__ xyzp,
    const float* __restrict__ new_xyz, int* __restrict__ idx_dn, float* __restrict__ new_xyzp) {
  int wave = threadIdx.x >> 6, lane = threadIdx.x & 63;
  int qid = blockIdx.x * 4 + wave;
  int b = qid >> 9, s = qid & (S - 1);
  const float4* xp = (const float4*)(xyzp + (size_t)b * N * 4);
  float qx = new_xyz[((size_t)b * S + s) * 3 + 0];
  float qy = new_xyz[((size_t)b * S + s) * 3 + 1];
  float qz = new_xyz[((size_t)b * S + s) * 3 + 2];
  float qq = __fadd_rn(__fadd_rn(__fmul_rn(qx, qx), __fmul_rn(qy, qy)), __fmul_rn(qz, qz));

  float lastD = -1.f; int lastI = -1;
  float curD; int curI;
  auto scan = [&]() {
    curD = 3e38f; curI = 0x7fffffff;
    for (int j = 0; j < 128; j++) {
      int i = lane + 64 * j;
      float4 p = xp[i];
      float rr  = __fadd_rn(__fadd_rn(__fmul_rn(p.x, p.x), __fmul_rn(p.y, p.y)), __fmul_rn(p.z, p.z));
      float dot = __fadd_rn(__fadd_rn(__fmul_rn(qx, p.x), __fmul_rn(qy, p.y)), __fmul_rn(qz, p.z));
      float d2 = __fsub_rn(__fadd_rn(qq, rr), __fmul_rn(2.0f, dot));
      bool gate   = (d2 > lastD) || (d2 == lastD && i > lastI);
      bool better = (d2 < curD) || (d2 == curD && i < curI);
      if (gate && better) { curD = d2; curI = i; }
    }
  };
  scan();
  int outI = 0;
  float4 nn0;
  #pragma unroll 1
  for (int r = 0; r < K; r++) {
    float mD = curD; int mI = curI; int mL = lane;
    #pragma unroll
    for (int off = 32; off > 0; off >>= 1) {
      float od = __shfl_xor(mD, off); int oi = __shfl_xor(mI, off); int ol = __shfl_xor(mL, off);
      if (od < mD || (od == mD && oi < mI)) { mD = od; mI = oi; mL = ol; }
    }
    if (lane == r) outI = mI;
    if (r == 0 && lane == 0) nn0 = xp[mI];
    if (lane == mL) { lastD = mD; lastI = mI; scan(); }
  }
  size_t base = ((size_t)b * S + s) * K;
  if (lane < K) idx_dn[base + lane] = outI;
  if (lane == 0) *(float4*)&new_xyzp[((size_t)b * S + s) * 4] = nn0;
}

// ---------------------------------------------------------------- kNN: 8192 queries vs 512 refs
__global__ __launch_bounds__(256) void knn_up_kernel(const float* __restrict__ xyzp,
    const float* __restrict__ new_xyz, int* __restrict__ idx_up) {
  int wave = threadIdx.x >> 6, lane = threadIdx.x & 63;
  int qid = blockIdx.x * 4 + wave;
  int b = qid >> 13, n = qid & (N - 1);
  const float4* xp = (const float4*)(xyzp + (size_t)b * N * 4);
  float4 qp = xp[n];
  float qx = qp.x, qy = qp.y, qz = qp.z;
  float qq = __fadd_rn(__fadd_rn(__fmul_rn(qx, qx), __fmul_rn(qy, qy)), __fmul_rn(qz, qz));
  float rx[8], ry[8], rz[8];
  #pragma unroll
  for (int j = 0; j < 8; j++) {
    int i = lane + 64 * j;
    rx[j] = new_xyz[((size_t)b * S + i) * 3 + 0];
    ry[j] = new_xyz[((size_t)b * S + i) * 3 + 1];
    rz[j] = new_xyz[((size_t)b * S + i) * 3 + 2];
  }
  float lastD = -1.f; int lastI = -1;
  float curD; int curI;
  auto scan = [&]() {
    curD = 3e38f; curI = 0x7fffffff;
    #pragma unroll
    for (int j = 0; j < 8; j++) {
      int i = lane + 64 * j;
      float rr  = __fadd_rn(__fadd_rn(__fmul_rn(rx[j], rx[j]), __fmul_rn(ry[j], ry[j])), __fmul_rn(rz[j], rz[j]));
      float dot = __fadd_rn(__fadd_rn(__fmul_rn(qx, rx[j]), __fmul_rn(qy, ry[j])), __fmul_rn(qz, rz[j]));
      float d2 = __fsub_rn(__fadd_rn(qq, rr), __fmul_rn(2.0f, dot));
      bool gate   = (d2 > lastD) || (d2 == lastD && i > lastI);
      bool better = (d2 < curD) || (d2 == curD && i < curI);
      if (gate && better) { curD = d2; curI = i; }
    }
  };
  scan();
  int outI = 0;
  #pragma unroll 1
  for (int r = 0; r < K; r++) {
    float mD = curD; int mI = curI; int mL = lane;
    #pragma unroll
    for (int off = 32; off > 0; off >>= 1) {
      float od = __shfl_xor(mD, off); int oi = __shfl_xor(mI, off); int ol = __shfl_xor(mL, off);
      if (od < mD || (od == mD && oi < mI)) { mD = od; mI = oi; mL = ol; }
    }
    if (lane == r) outI = mI;
    if (lane == mL) { lastD = mD; lastI = mI; scan(); }
  }
  size_t base = ((size_t)b * N + n) * K;
  if (lane < K) idx_up[base + lane] = outI;
}

// ---------------------------------------------------------------- td layer 0 (131 -> 128, MFMA)
constexpr int KS0 = 168;
__global__ __launch_bounds__(256) void td0_mfma(const float* __restrict__ xyzp,
    const float* __restrict__ new_xyz, const float* __restrict__ feats,
    const int* __restrict__ idx_dn, const float* __restrict__ w0, const float* __restrict__ b0,
    float* __restrict__ act0) {
  __shared__ short WT[128 * KS0];
  __shared__ short Abuf[4][16 * KS0];
  __shared__ int nbs[4][16];
  const int t = threadIdx.x, w = t >> 6, lane = t & 63;
  const int c0 = lane & 15, quad = lane >> 4;
  const int row0 = blockIdx.x * 64 + w * 16;
  const int bI = row0 >> 13;
  if (lane < 16) {
    int nb = idx_dn[row0 + lane];
    nbs[w][lane] = nb;
    int s = ((row0 + lane) >> 4) & (S - 1);
    #pragma unroll
    for (int d = 0; d < 3; d++)
      Abuf[w][lane * KS0 + d] =
          f2bf(xyzp[((size_t)bI * N + nb) * 4 + d] - new_xyz[((size_t)bI * S + s) * 3 + d]);
    for (int k2 = 131; k2 < 160; k2++) Abuf[w][lane * KS0 + k2] = 0;
  }
  #pragma unroll 4
  for (int i = 0; i < 32; i++) {
    int idx = lane + 64 * i;
    int r = idx >> 7, c = idx & 127;
    int nb = nbs[w][r];
    Abuf[w][r * KS0 + 3 + c] = f2bf(feats[((size_t)bI * N + nb) * F + c]);
  }
  #pragma unroll 4
  for (int i = 0; i < 66; i++) {
    int g = t + 256 * i;
    if (g < 131 * 128) {
      int kx = g >> 7, n = g & 127;
      WT[n * KS0 + kx] = f2bf(w0[g]);
    }
  }
  #pragma unroll
  for (int i = 0; i < 15; i++) {
    int g2 = t + 256 * i;
    int kz = 131 + (g2 >> 7), n = g2 & 127;
    if (kz < 160) WT[n * KS0 + kz] = 0;
  }
  __syncthreads();
  v4f acc[8];
  #pragma unroll
  for (int nt = 0; nt < 8; nt++) { float bvv = b0[nt * 16 + c0]; acc[nt] = (v4f){bvv, bvv, bvv, bvv}; }
  #pragma unroll
  for (int ks = 0; ks < 5; ks++) {
    v8s a = *(const v8s*)&Abuf[w][c0 * KS0 + ks * 32 + quad * 8];
    #pragma unroll
    for (int nt = 0; nt < 8; nt++) {
      v8s bf = *(const v8s*)&WT[(nt * 16 + c0) * KS0 + ks * 32 + quad * 8];
      acc[nt] = __builtin_amdgcn_mfma_f32_16x16x32_bf16(a, bf, acc[nt], 0, 0, 0);
    }
  }
  #pragma unroll
  for (int nt = 0; nt < 8; nt++)
    #pragma unroll
    for (int r = 0; r < 4; r++)
      act0[(size_t)(row0 + quad * 4 + r) * F + nt * 16 + c0] = acc[nt][r];
}

// ---------------------------------------------------------------- batchnorm stats
__global__ __launch_bounds__(256) void bn_reduce_kernel(const float* __restrict__ x,
                                                        float* __restrict__ sums) {
  __shared__ float ls[256], ls2[256];
  int t = threadIdx.x;
  size_t base = (size_t)blockIdx.x * 65536 + t;
  float s = 0.f, s2 = 0.f;
  for (int i = 0; i < 256; i++) {
    float v = x[base + (size_t)i * 256];
    s += v; s2 = fmaf(v, v, s2);
  }
  ls[t] = s; ls2[t] = s2; __syncthreads();
  if (t < 128) {
    s = ls[t] + ls[t + 128]; s2 = ls2[t] + ls2[t + 128];
    atomicAdd(&sums[t], s); atomicAdd(&sums[128 + t], s2);
  }
}

__global__ void bn_finalize_kernel(const float* __restrict__ sums, const float* __restrict__ g,
    const float* __restrict__ bta, float* __restrict__ scale, float* __restrict__ shift) {
  int t = threadIdx.x;
  float m = sums[t] * (1.f / 32768.f);
  float var = sums[128 + t] * (1.f / 32768.f) - m * m;
  float rstd = rsqrtf(var + EPS);
  float sc = g[t] * rstd;
  scale[t] = sc;
  shift[t] = bta[t] - m * sc;
}

// ---------------------------------------------------------------- td layer 1 (128 -> 128, MFMA)
constexpr int KS1 = 136;
__global__ __launch_bounds__(256) void td1_mfma(const float* __restrict__ act0,
    const float* __restrict__ scale, const float* __restrict__ shift,
    const float* __restrict__ w1, const float* __restrict__ b1, float* __restrict__ act1) {
  __shared__ short WT[128 * KS1];
  __shared__ short Abuf[4][16 * KS1];
  __shared__ float scs[128], shs[128];
  const int t = threadIdx.x, w = t >> 6, lane = t & 63;
  const int c0 = lane & 15, quad = lane >> 4;
  const int row0 = blockIdx.x * 64 + w * 16;
  if (t < 128) { scs[t] = scale[t]; shs[t] = shift[t]; }
  #pragma unroll 4
  for (int i = 0; i < 64; i++) {
    int g = t + 256 * i;
    int kx = g >> 7, n = g & 127;
    WT[n * KS1 + kx] = f2bf(w1[g]);
  }
  __syncthreads();
  #pragma unroll 4
  for (int i = 0; i < 32; i++) {
    int idx = lane + 64 * i;
    int r = idx >> 7, c = idx & 127;
    float vv = fmaxf(fmaf(act0[(size_t)(row0 + r) * F + c], scs[c], shs[c]), 0.f);
    Abuf[w][r * KS1 + c] = f2bf(vv);
  }
  v4f acc[8];
  #pragma unroll
  for (int nt = 0; nt < 8; nt++) { float bvv = b1[nt * 16 + c0]; acc[nt] = (v4f){bvv, bvv, bvv, bvv}; }
  #pragma unroll
  for (int ks = 0; ks < 4; ks++) {
    v8s a = *(const v8s*)&Abuf[w][c0 * KS1 + ks * 32 + quad * 8];
    #pragma unroll
    for (int nt = 0; nt < 8; nt++) {
      v8s bf = *(const v8s*)&WT[(nt * 16 + c0) * KS1 + ks * 32 + quad * 8];
      acc[nt] = __builtin_amdgcn_mfma_f32_16x16x32_bf16(a, bf, acc[nt], 0, 0, 0);
    }
  }
  #pragma unroll
  for (int nt = 0; nt < 8; nt++)
    #pragma unroll
    for (int r = 0; r < 4; r++)
      act1[(size_t)(row0 + quad * 4 + r) * F + nt * 16 + c0] = acc[nt][r];
}

// ---------------------------------------------------------------- BN+relu+max over K
__global__ __launch_bounds__(128) void maxpool_kernel(const float* __restrict__ act1,
    const float* __restrict__ scale, const float* __restrict__ shift, float* __restrict__ new_feats) {
  int bs = blockIdx.x, t = threadIdx.x;
  float sc = scale[t], sh = shift[t];
  float m = -3e38f;
  for (int k = 0; k < K; k++) {
    float v = fmaxf(fmaf(act1[((size_t)bs * K + k) * F + t], sc, sh), 0.f);
    m = fmaxf(m, v);
  }
  new_feats[(size_t)bs * F + t] = m;
}

// ---------------------------------------------------------------- new_x = new_feats @ w_gkern + b
__global__ __launch_bounds__(128) void rowgemm_kernel(const float* __restrict__ in,
    const float* __restrict__ w, const float* __restrict__ bias, float* __restrict__ out) {
  int r = blockIdx.x, t = threadIdx.x;
  __shared__ float row[128];
  row[t] = in[(size_t)r * F + t]; __syncthreads();
  float acc = bias[t];
  for (int i = 0; i < F; i++) acc = fmaf(row[i], w[i * F + t], acc);
  out[(size_t)r * F + t] = acc;
}

// ---------------------------------------------------------------- kk/vv = new_x @ w_k / w_v
__global__ __launch_bounds__(128) void kv_kernel(const float* __restrict__ new_x,
    const float* __restrict__ wk, const float* __restrict__ wvp,
    float* __restrict__ kk, float* __restrict__ vv) {
  int r = blockIdx.x, t = threadIdx.x;
  __shared__ float row[128];
  row[t] = new_x[(size_t)r * F + t]; __syncthreads();
  float ak = 0.f, av = 0.f;
  for (int i = 0; i < F; i++) {
    float x = row[i];
    ak = fmaf(x, wk[i * F + t], ak);
    av = fmaf(x, wvp[i * F + t], av);
  }
  kk[(size_t)r * F + t] = ak;
  vv[(size_t)r * F + t] = av;
}

// ---------------------------------------------------------------- q = (feats @ w_kern + b) @ w_q  (MFMA)
__global__ __launch_bounds__(256) void q_mfma(const float* __restrict__ feats,
    const float* __restrict__ w_kern, const float* __restrict__ b_kern,
    const float* __restrict__ w_q, float* __restrict__ q) {
  __shared__ short WT[128 * KS1];
  __shared__ short Abuf[4][16 * KS1];
  const int t = threadIdx.x, w = t >> 6, lane = t & 63;
  const int c0 = lane & 15, quad = lane >> 4;
  const int row0 = blockIdx.x * 64 + w * 16;
  #pragma unroll 4
  for (int i = 0; i < 32; i++) {
    int idx = lane + 64 * i;
    int r = idx >> 7, c = idx & 127;
    Abuf[w][r * KS1 + c] = f2bf(feats[(size_t)(row0 + r) * F + c]);
  }
  #pragma unroll 4
  for (int i = 0; i < 64; i++) {
    int g = t + 256 * i;
    int kx = g >> 7, n = g & 127;
    WT[n * KS1 + kx] = f2bf(w_kern[g]);
  }
  __syncthreads();
  v4f acc[8];
  #pragma unroll
  for (int nt = 0; nt < 8; nt++) { float bvv = b_kern[nt * 16 + c0]; acc[nt] = (v4f){bvv, bvv, bvv, bvv}; }
  #pragma unroll
  for (int ks = 0; ks < 4; ks++) {
    v8s a = *(const v8s*)&Abuf[w][c0 * KS1 + ks * 32 + quad * 8];
    #pragma unroll
    for (int nt = 0; nt < 8; nt++) {
      v8s bf = *(const v8s*)&WT[(nt * 16 + c0) * KS1 + ks * 32 + quad * 8];
      acc[nt] = __builtin_amdgcn_mfma_f32_16x16x32_bf16(a, bf, acc[nt], 0, 0, 0);
    }
  }
  __syncthreads();
  #pragma unroll 4
  for (int i = 0; i < 64; i++) {
    int g = t + 256 * i;
    int kx = g >> 7, n = g & 127;
    WT[n * KS1 + kx] = f2bf(w_q[g]);
  }
  #pragma unroll
  for (int nt = 0; nt < 8; nt++)
    #pragma unroll
    for (int r = 0; r < 4; r++)
      Abuf[w][(quad * 4 + r) * KS1 + nt * 16 + c0] = f2bf(acc[nt][r]);
  __syncthreads();
  v4f acc2[8];
  #pragma unroll
  for (int nt = 0; nt < 8; nt++) acc2[nt] = (v4f){0.f, 0.f, 0.f, 0.f};
  #pragma unroll
  for (int ks = 0; ks < 4; ks++) {
    v8s a = *(const v8s*)&Abuf[w][c0 * KS1 + ks * 32 + quad * 8];
    #pragma unroll
    for (int nt = 0; nt < 8; nt++) {
      v8s bf = *(const v8s*)&WT[(nt * 16 + c0) * KS1 + ks * 32 + quad * 8];
      acc2[nt] = __builtin_amdgcn_mfma_f32_16x16x32_bf16(a, bf, acc2[nt], 0, 0, 0);
    }
  }
  #pragma unroll
  for (int nt = 0; nt < 8; nt++)
    #pragma unroll
    for (int r = 0; r < 4; r++)
      q[(size_t)(row0 + quad * 4 + r) * F + nt * 16 + c0] = acc2[nt][r];
}

// ---------------------------------------------------------------- fused neighbor attention (MFMA bf16)
constexpr int WS = 136;
constexpr int VS = 132;

__global__ __launch_bounds__(256) void attn_kernel(const float* __restrict__ xyzp,
    const float* __restrict__ q, const float* __restrict__ kk, const float* __restrict__ vv,
    const float* __restrict__ new_xyzp, const int* __restrict__ idx_up,
    const float* __restrict__ feats,
    const float* __restrict__ pe_w1, const float* __restrict__ pe_b1,
    const float* __restrict__ pe_w2, const float* __restrict__ pe_b2,
    const float* __restrict__ at_w1, const float* __restrict__ at_b1,
    const float* __restrict__ at_w2, const float* __restrict__ at_b2,
    const float* __restrict__ w_agg, const float* __restrict__ b_agg,
    float* __restrict__ out) {
  __shared__ short WT[128 * WS];
  __shared__ short Abuf[4][16 * WS];
  __shared__ short WVb[4][16 * VS];
  __shared__ float qsh[4][128];
  __shared__ float resh[4][128];
  __shared__ float pdsh[4][16][4];
  __shared__ int   nbsh[4][16];

  const int t = threadIdx.x, w = t >> 6, lane = t & 63;
  const int c0 = lane & 15, quad = lane >> 4;
  const int p = blockIdx.x * 4 + w;
  const int b = p >> 13;

  qsh[w][lane]      = q[(size_t)p * H + lane];
  qsh[w][lane + 64] = q[(size_t)p * H + lane + 64];
  if (lane < 16) nbsh[w][lane] = idx_up[(size_t)p * K + lane];
  {
    int k = lane >> 2, d = lane & 3;
    pdsh[w][k][d] = xyzp[(size_t)p * 4 + d] - new_xyzp[((size_t)b * S + nbsh[w][k]) * 4 + d];
  }
  #pragma unroll
  for (int cc = 0; cc < 2; cc++) {
    int c = cc * 64 + lane;
    float bb = pe_b1[c];
    float w0 = pe_w1[c], w1 = pe_w1[128 + c], w2 = pe_w1[256 + c], w3 = pe_w1[384 + c];
    #pragma unroll
    for (int k = 0; k < 16; k++) {
      float h = bb + pdsh[w][k][0] * w0 + pdsh[w][k][1] * w1 + pdsh[w][k][2] * w2 + pdsh[w][k][3] * w3;
      Abuf[w][k * WS + c] = f2bf(fmaxf(h, 0.f));
    }
  }

  auto stageW = [&](const float* __restrict__ Wg) {
    __syncthreads();
    #pragma unroll 4
    for (int i = 0; i < 64; i++) {
      int g = t + 256 * i;
      int kx = g >> 7, n = g & 127;
      WT[n * WS + kx] = f2bf(Wg[g]);
    }
    __syncthreads();
  };
  auto gemm = [&](const float* __restrict__ bias, v4f* acc) {
    #pragma unroll
    for (int nt = 0; nt < 8; nt++) {
      float bv = bias[nt * 16 + c0];
      acc[nt] = (v4f){bv, bv, bv, bv};
    }
    #pragma unroll
    for (int ks = 0; ks < 4; ks++) {
      v8s a = *(const v8s*)&Abuf[w][c0 * WS + ks * 32 + quad * 8];
      #pragma unroll
      for (int nt = 0; nt < 8; nt++) {
        v8s bf = *(const v8s*)&WT[(nt * 16 + c0) * WS + ks * 32 + quad * 8];
        acc[nt] = __builtin_amdgcn_mfma_f32_16x16x32_bf16(a, bf, acc[nt], 0, 0, 0);
      }
    }
  };

  stageW(pe_w2);
  v4f pe[8];
  gemm(pe_b2, pe);

  #pragma unroll
  for (int nt = 0; nt < 8; nt++) {
    #pragma unroll
    for (int r = 0; r < 4; r++) {
      int krow = quad * 4 + r;
      int c = nt * 16 + c0;
      int nb = nbsh[w][krow];
      float pev = pe[nt][r];
      float avv = qsh[w][c] - kk[((size_t)b * S + nb) * H + c] + pev;
      float wvv = vv[((size_t)b * S + nb) * H + c] + pev;
      Abuf[w][krow * WS + c] = f2bf(avv);
      WVb[w][krow * VS + c] = f2bf(wvv);
    }
  }

  stageW(at_w1);
  v4f h1[8];
  gemm(at_b1, h1);
  #pragma unroll
  for (int nt = 0; nt < 8; nt++)
    #pragma unroll
    for (int r = 0; r < 4; r++)
      Abuf[w][(quad * 4 + r) * WS + nt * 16 + c0] = f2bf(fmaxf(h1[nt][r], 0.f));

  stageW(at_w2);
  v4f lg[8];
  gemm(at_b2, lg);

  const float scale = 0.08838834764831845f;
  #pragma unroll
  for (int nt = 0; nt < 8; nt++) {
    float l0 = lg[nt][0] * scale, l1 = lg[nt][1] * scale;
    float l2 = lg[nt][2] * scale, l3 = lg[nt][3] * scale;
    float m = fmaxf(fmaxf(l0, l1), fmaxf(l2, l3));
    m = fmaxf(m, __shfl_xor(m, 16));
    m = fmaxf(m, __shfl_xor(m, 32));
    float e0 = expf(l0 - m), e1 = expf(l1 - m), e2 = expf(l2 - m), e3 = expf(l3 - m);
    float ssum = e0 + e1 + e2 + e3;
    ssum += __shfl_xor(ssum, 16);
    ssum += __shfl_xor(ssum, 32);
    float inv = 1.f / ssum;
    int c = nt * 16 + c0;
    float partial =
        e0 * bf2f(WVb[w][(quad * 4 + 0) * VS + c]) + e1 * bf2f(WVb[w][(quad * 4 + 1) * VS + c]) +
        e2 * bf2f(WVb[w][(quad * 4 + 2) * VS + c]) + e3 * bf2f(WVb[w][(quad * 4 + 3) * VS + c]);
    partial += __shfl_xor(partial, 16);
    partial += __shfl_xor(partial, 32);
    if (quad == 0) resh[w][c] = partial * inv;
  }

  #pragma unroll
  for (int cc = 0; cc < 2; cc++) {
    int c = cc * 64 + lane;
    float o = b_agg[c];
    for (int i = 0; i < H; i++) o = fmaf(resh[w][i], w_agg[i * H + c], o);
    out[(size_t)p * F + c] = o + feats[(size_t)p * F + c];
  }
}

// ================================================================ host
extern "C" void kernel_launch(void* const* d_in, const int* in_sizes, int n_in,
                              void* d_out, int out_size, void* d_ws, size_t ws_size,
                              hipStream_t stream) {
  (void)in_sizes; (void)n_in; (void)out_size; (void)ws_size;
  const float* xyzp    = (const float*)d_in[0];
  const float* features= (const float*)d_in[1];
  const float* ln_g    = (const float*)d_in[2];
  const float* ln_b    = (const float*)d_in[3];
  const float* td_w0   = (const float*)d_in[4];
  const float* td_b0   = (const float*)d_in[5];
  const float* bn0_g   = (const float*)d_in[6];
  const float* bn0_b   = (const float*)d_in[7];
  const float* td_w1   = (const float*)d_in[8];
  const float* td_b1   = (const float*)d_in[9];
  const float* bn1_g   = (const float*)d_in[10];
  const float* bn1_b   = (const float*)d_in[11];
  const float* w_kern  = (const float*)d_in[12];
  const float* b_kern  = (const float*)d_in[13];
  const float* w_gkern = (const float*)d_in[14];
  const float* b_gkern = (const float*)d_in[15];
  const float* w_agg   = (const float*)d_in[16];
  const float* b_agg   = (const float*)d_in[17];
  const float* w_q     = (const float*)d_in[18];
  const float* w_k     = (const float*)d_in[19];
  const float* w_v     = (const float*)d_in[20];
  const float* pe_w1   = (const float*)d_in[21];
  const float* pe_b1   = (const float*)d_in[22];
  const float* pe_w2   = (const float*)d_in[23];
  const float* pe_b2   = (const float*)d_in[24];
  const float* at_w1   = (const float*)d_in[25];
  const float* at_b1   = (const float*)d_in[26];
  const float* at_w2   = (const float*)d_in[27];
  const float* at_b2   = (const float*)d_in[28];
  float* out = (float*)d_out;

  float* wsf = (float*)d_ws;
  float* feats     = wsf + 0;           // 4194304
  float* q         = wsf + 4194304;     // 4194304
  float* act0      = wsf + 8388608;     // 4194304
  float* act1      = wsf + 12582912;    // 4194304
  float* new_feats = wsf + 16777216;    // 262144
  float* new_x     = wsf + 17039360;    // 262144
  float* kk        = wsf + 17301504;    // 262144
  float* vv        = wsf + 17563648;    // 262144
  float* new_xyz   = wsf + 17825792;    // 6144
  float* new_xyzp  = wsf + 17831936;    // 8192
  float* sums0     = wsf + 17840128;    // 256
  float* sums1     = wsf + 17840384;    // 256
  float* sc0       = wsf + 17840640;    // 128
  float* sh0       = wsf + 17840768;    // 128
  float* sc1       = wsf + 17840896;    // 128
  float* sh1       = wsf + 17841024;    // 128
  int* idx_dn  = (int*)(wsf + 17841152);
  int* idx_up  = idx_dn + 32768;

  hipMemsetAsync(sums0, 0, 512 * sizeof(float), stream);
  ln_kernel<<<B * N, 128, 0, stream>>>(features, ln_g, ln_b, feats);
  fps_kernel<<<B, 256, 0, stream>>>(xyzp, new_xyz);
  knn_dn_kernel<<<512, 256, 0, stream>>>(xyzp, new_xyz, idx_dn, new_xyzp);
  knn_up_kernel<<<8192, 256, 0, stream>>>(xyzp, new_xyz, idx_up);
  td0_mfma<<<512, 256, 0, stream>>>(xyzp, new_xyz, feats, idx_dn, td_w0, td_b0, act0);
  bn_reduce_kernel<<<64, 256, 0, stream>>>(act0, sums0);
  bn_finalize_kernel<<<1, 128, 0, stream>>>(sums0, bn0_g, bn0_b, sc0, sh0);
  td1_mfma<<<512, 256, 0, stream>>>(act0, sc0, sh0, td_w1, td_b1, act1);
  bn_reduce_kernel<<<64, 256, 0, stream>>>(act1, sums1);
  bn_finalize_kernel<<<1, 128, 0, stream>>>(sums1, bn1_g, bn1_b, sc1, sh1);
  maxpool_kernel<<<B * S, 128, 0, stream>>>(act1, sc1, sh1, new_feats);
  rowgemm_kernel<<<B * S, 128, 0, stream>>>(new_feats, w_gkern, b_gkern, new_x);
  kv_kernel<<<B * S, 128, 0, stream>>>(new_x, w_k, w_v, kk, vv);
  q_mfma<<<512, 256, 0, stream>>>(feats, w_kern, b_kern, w_q, q);
  attn_kernel<<<8192, 256, 0, stream>>>(xyzp, q, kk, vv, new_xyzp, idx_up, feats,
      pe_w1, pe_b1, pe_w2, pe_b2, at_w1, at_b1, at_w2, at_b2, w_agg, b_agg, out);
}